// Round 10
// baseline (861.046 us; speedup 1.0000x reference)
//
#include <hip/hip_runtime.h>
#include <math.h>

typedef __attribute__((ext_vector_type(8))) short short8;   // 8 bf16 (MFMA A/B frag)
typedef __attribute__((ext_vector_type(4))) float f32x4;    // MFMA acc frag
typedef __attribute__((ext_vector_type(2))) float f32x2;
typedef __attribute__((ext_vector_type(4))) unsigned u32x4;

#define PI_OVER_CUTOFF 0.31415926535897932f
#define SLOPE 0.015f

__device__ __forceinline__ unsigned short f2bf(float x) {
    unsigned u = __float_as_uint(x);
    return (unsigned short)((u + 0x7FFFu + ((u >> 16) & 1u)) >> 16);   // RNE
}
// packed f32x2 -> bf16x2, RNE, one instruction. D.lo = cvt(S0), D.hi = cvt(S1).
__device__ __forceinline__ unsigned cvt_pk_bf16(float lo, float hi) {
    unsigned r;
    asm("v_cvt_pk_bf16_f32 %0, %1, %2" : "=v"(r) : "v"(lo), "v"(hi));
    return r;
}
__device__ __forceinline__ short8 pack4(unsigned a, unsigned b, unsigned c, unsigned d) {
    u32x4 t = {a, b, c, d};
    return __builtin_bit_cast(short8, t);
}
// elementwise bf16 product of two bf16x8 frags, computed in f32, repacked bf16
__device__ __forceinline__ short8 mulbf8(short8 w, short8 v) {
    u32x4 uw = __builtin_bit_cast(u32x4, w);
    u32x4 uv = __builtin_bit_cast(u32x4, v);
    unsigned r0, r1, r2, r3;
#define MB(i, r)                                                         \
    {                                                                    \
        float wl = __uint_as_float(uw[i] << 16);                         \
        float wh = __uint_as_float(uw[i] & 0xFFFF0000u);                 \
        float vl = __uint_as_float(uv[i] << 16);                         \
        float vh = __uint_as_float(uv[i] & 0xFFFF0000u);                 \
        r = cvt_pk_bf16(wl * vl, wh * vh);                               \
    }
    MB(0, r0) MB(1, r1) MB(2, r2) MB(3, r3)
#undef MB
    return pack4(r0, r1, r2, r3);
}

// async global(per-lane) -> LDS(wave-uniform base, lane*16B) 16-byte copy
#define GLOAD_LDS16(g, l)                                                                      \
    __builtin_amdgcn_global_load_lds((const __attribute__((address_space(1))) unsigned*)(g),   \
                                     (__attribute__((address_space(3))) unsigned*)(l), 16, 0, 0)

// ---- kernel 0: weights -> bf16 ------------------------------------------------
// w1p: [128][64] row-major, NOT swizzled (B-frag reads from global, L1-hot).
// wsrc: w2|w3|wo each [128][128], PRE-SWIZZLED: (c,k) at c*128 + (k ^ ((c&15)<<3))
//       -> linear global_load_lds + swizzled ds_read is conflict-free (R6-verified).
__global__ void prep_weights(const float* __restrict__ w1, const float* __restrict__ w2,
                             const float* __restrict__ w3, const float* __restrict__ wo,
                             unsigned short* __restrict__ w1p, unsigned short* __restrict__ wsrc) {
    int i = blockIdx.x * 256 + threadIdx.x;
    unsigned short* w2s = wsrc;
    unsigned short* w3s = wsrc + 128 * 128;
    unsigned short* wos = w3s + 128 * 128;
    if (i < 128 * 64) {
        int c = i >> 6, k = i & 63;
        w1p[i] = (k < 50) ? f2bf(w1[c * 50 + k]) : (unsigned short)0;  // pad K 50->64
    }
    if (i < 128 * 128) {
        int c = i >> 7, k = i & 127;
        int d = c * 128 + (k ^ ((c & 15) << 3));
        w2s[d] = f2bf(w2[i]);
        w3s[d] = f2bf(w3[i]);
        wos[d] = f2bf(wo[i] + ((c == k) ? 1.0f : 0.0f));  // fold "+e" residual
    }
}

// ---------------- kernel 1: vp = v @ lin_w.T  -> bf16 [N][128] -----------------
__global__ __launch_bounds__(256) void vp_gemm(const float* __restrict__ v,
                                               const float* __restrict__ lin_w,
                                               unsigned short* __restrict__ vp, int nnodes) {
    const int tid = threadIdx.x;
    const int lane = tid & 63;
    const int wv = tid >> 6;          // wave 0..3 -> col strip of 32
    const int l15 = lane & 15;
    const int l4 = lane >> 4;
    const int r0 = blockIdx.x * 64;
    const int c0 = wv * 32;

    f32x4 acc[4][2] = {};
#pragma unroll
    for (int kf = 0; kf < 4; ++kf) {
        short8 a[4];
#pragma unroll
        for (int mf = 0; mf < 4; ++mf) {
            int row = r0 + mf * 16 + l15;
            f32x4 x0 = {}, x1 = {};
            if (row < nnodes) {
                const float* p = v + (size_t)row * 128 + kf * 32 + l4 * 8;
                x0 = *reinterpret_cast<const f32x4*>(p);
                x1 = *reinterpret_cast<const f32x4*>(p + 4);
            }
            a[mf] = pack4(cvt_pk_bf16(x0[0], x0[1]), cvt_pk_bf16(x0[2], x0[3]),
                          cvt_pk_bf16(x1[0], x1[1]), cvt_pk_bf16(x1[2], x1[3]));
        }
        short8 b[2];
#pragma unroll
        for (int nf = 0; nf < 2; ++nf) {
            const float* p = lin_w + (size_t)(c0 + nf * 16 + l15) * 128 + kf * 32 + l4 * 8;
            f32x4 x0 = *reinterpret_cast<const f32x4*>(p);
            f32x4 x1 = *reinterpret_cast<const f32x4*>(p + 4);
            b[nf] = pack4(cvt_pk_bf16(x0[0], x0[1]), cvt_pk_bf16(x0[2], x0[3]),
                          cvt_pk_bf16(x1[0], x1[1]), cvt_pk_bf16(x1[2], x1[3]));
        }
#pragma unroll
        for (int mf = 0; mf < 4; ++mf)
#pragma unroll
            for (int nf = 0; nf < 2; ++nf)
                acc[mf][nf] = __builtin_amdgcn_mfma_f32_16x16x32_bf16(a[mf], b[nf], acc[mf][nf], 0, 0, 0);
    }
#pragma unroll
    for (int mf = 0; mf < 4; ++mf)
#pragma unroll
        for (int nf = 0; nf < 2; ++nf)
#pragma unroll
            for (int q = 0; q < 4; ++q) {
                int row = r0 + mf * 16 + l4 * 4 + q;
                if (row < nnodes)
                    vp[(size_t)row * 128 + c0 + nf * 16 + l15] = f2bf(acc[mf][nf][q]);
            }
}

// ---- kernel 2: persistent, M=64/wave (R6 bodies), weights staged ONCE --------
// 4 waves x 64 edges; w2|w3|wo resident in 96KB LDS; h private 16KB/wave (64KB);
// 160KB total, 1 block/CU. launch_bounds(256,1): 512-reg budget -> NO spill at
// ~300-reg demand (R9 lesson: M=64 needs the full budget; TLP < ILP here).
// ONE barrier (after staging); steady-state tile loop is barrier-free.
__global__ __launch_bounds__(256, 1) void fused_edge(
    const float* __restrict__ dist, const float* __restrict__ dist_emb,
    const int* __restrict__ edge_index,
    const float* __restrict__ b1, const float* __restrict__ b2,
    const float* __restrict__ b3, const float* __restrict__ bo,
    const unsigned short* __restrict__ vp,
    const unsigned short* __restrict__ w1p, const unsigned short* __restrict__ wsrc,
    float* __restrict__ out, int ntiles) {
    __shared__ __align__(16) unsigned short wlds[3 * 16384];  // 96KB: w2|w3|wo swizzled
    __shared__ __align__(16) unsigned char lds_h[4][16384];   // per-wave [64][256B] swizzled

    const int tid = threadIdx.x;
    const int lane = tid & 63;
    const int wv = tid >> 6;
    const int l15 = lane & 15;
    const int l4 = lane >> 4;
    unsigned char* hb = lds_h[wv];

    // ---- stage w2|w3|wo once: 96 chunks of 1KB, 24 per wave ----
#pragma unroll
    for (int it = 0; it < 24; ++it) {
        int chunk = it * 4 + wv;
        GLOAD_LDS16(wsrc + chunk * 512 + lane * 8, &wlds[chunk * 512]);
    }

    // ---- hoist biases (col = nf*16 + l15; identity folded into wo) ----
    float bb1[8], bb2[8], bb3[8], bbo[8];
#pragma unroll
    for (int nf = 0; nf < 8; ++nf) {
        bb1[nf] = b1[nf * 16 + l15];
        bb2[nf] = b2[nf * 16 + l15];
        bb3[nf] = b3[nf * 16 + l15];
        bbo[nf] = bo[nf * 16 + l15];
    }

#define WL_READ(widx, nf, kf) \
    (*reinterpret_cast<const short8*>(&wlds[(widx) * 16384 + ((nf) * 16 + l15) * 128 + (((kf) * 32 + l4 * 8) ^ (l15 << 3))]))
#define HB_READ(mf, kf) \
    (*reinterpret_cast<const short8*>(hb + ((mf) * 16 + l15) * 256 + (((kf) * 64 + l4 * 16) ^ (l15 << 4))))

#define INIT_ACC(bb)                                                                \
    _Pragma("unroll")                                                               \
    for (int nf = 0; nf < 8; ++nf) {                                                \
        float b = (bb)[nf];                                                         \
        _Pragma("unroll")                                                           \
        for (int mf = 0; mf < 4; ++mf) acc[mf][nf] = (f32x4){b, b, b, b};           \
    }

#define EPILOGUE_TO_LDS()                                                           \
    _Pragma("unroll")                                                               \
    for (int mf = 0; mf < 4; ++mf)                                                  \
        _Pragma("unroll")                                                           \
        for (int nf = 0; nf < 8; ++nf) {                                            \
            f32x4 vv = acc[mf][nf];                                                 \
            _Pragma("unroll")                                                       \
            for (int q = 0; q < 4; ++q) vv[q] = fmaxf(vv[q], SLOPE * vv[q]);        \
            unsigned p01 = cvt_pk_bf16(vv[0], vv[1]);                               \
            unsigned p23 = cvt_pk_bf16(vv[2], vv[3]);                               \
            int col2 = (nf * 16 + l15) * 2;                                         \
            int rb = mf * 16 + l4 * 4;                                              \
            *(unsigned short*)(hb + (rb + 0) * 256 + (col2 ^ ((l4 * 4 + 0) << 4))) = (unsigned short)p01;         \
            *(unsigned short*)(hb + (rb + 1) * 256 + (col2 ^ ((l4 * 4 + 1) << 4))) = (unsigned short)(p01 >> 16); \
            *(unsigned short*)(hb + (rb + 2) * 256 + (col2 ^ ((l4 * 4 + 2) << 4))) = (unsigned short)p23;         \
            *(unsigned short*)(hb + (rb + 3) * 256 + (col2 ^ ((l4 * 4 + 3) << 4))) = (unsigned short)(p23 >> 16); \
        }

    __syncthreads();   // the ONLY barrier: weights staged (implicit vmcnt drain)

    f32x4 acc[4][8];
    for (int t = blockIdx.x; t < ntiles; t += gridDim.x) {
        const long e0 = (long)t * 256 + wv * 64;

        // ===== stage 1: h1 = leaky(emb @ w1.T + b1)  [w1 B-frags from global] =====
        INIT_ACC(bb1)
#pragma unroll
        for (int kf = 0; kf < 2; ++kf) {
            short8 a[4];
#pragma unroll
            for (int mf = 0; mf < 4; ++mf) {
                const float* src = dist_emb + (e0 + mf * 16 + l15) * 50 + kf * 32 + l4 * 8;
                unsigned pk[4];
#pragma unroll
                for (int p = 0; p < 4; ++p) {
                    int k2 = kf * 32 + l4 * 8 + 2 * p;
                    f32x2 x = (k2 < 50) ? *reinterpret_cast<const f32x2*>(src + 2 * p)
                                        : (f32x2){0.f, 0.f};
                    pk[p] = cvt_pk_bf16(x[0], x[1]);
                }
                a[mf] = pack4(pk[0], pk[1], pk[2], pk[3]);
            }
#pragma unroll
            for (int nf = 0; nf < 8; ++nf) {
                short8 b = *reinterpret_cast<const short8*>(w1p + (nf * 16 + l15) * 64 + kf * 32 + l4 * 8);
#pragma unroll
                for (int mf = 0; mf < 4; ++mf)
                    acc[mf][nf] = __builtin_amdgcn_mfma_f32_16x16x32_bf16(a[mf], b, acc[mf][nf], 0, 0, 0);
            }
        }
        EPILOGUE_TO_LDS()

        // ===== stage 2: h2 = leaky(h1 @ w2.T + b2) =====
        INIT_ACC(bb2)
#pragma unroll
        for (int kf = 0; kf < 4; ++kf) {
            short8 a[4];
#pragma unroll
            for (int mf = 0; mf < 4; ++mf) a[mf] = HB_READ(mf, kf);
#pragma unroll
            for (int nf = 0; nf < 8; ++nf) {
                short8 b = WL_READ(0, nf, kf);
#pragma unroll
                for (int mf = 0; mf < 4; ++mf)
                    acc[mf][nf] = __builtin_amdgcn_mfma_f32_16x16x32_bf16(a[mf], b, acc[mf][nf], 0, 0, 0);
            }
        }
        EPILOGUE_TO_LDS()

        // ===== stage 3: W = (h2 @ w3.T + b3) * C(dist) =====
        {
            // vp gather + dist issued at stage-3 top (R6 placement, 1 stage cover)
            int jm[4];
#pragma unroll
            for (int mf = 0; mf < 4; ++mf)
                jm[mf] = edge_index[e0 + mf * 16 + l15] * 128;
            short8 vpr[4][4];
#pragma unroll
            for (int mf = 0; mf < 4; ++mf)
#pragma unroll
                for (int kf = 0; kf < 4; ++kf)
                    vpr[mf][kf] = *reinterpret_cast<const short8*>(vp + jm[mf] + kf * 32 + l4 * 8);
            float dd[4][4];
#pragma unroll
            for (int mf = 0; mf < 4; ++mf)
#pragma unroll
                for (int q = 0; q < 4; ++q)
                    dd[mf][q] = dist[e0 + mf * 16 + l4 * 4 + q];

            INIT_ACC(bb3)
#pragma unroll
            for (int kf = 0; kf < 4; ++kf) {
                short8 a[4];
#pragma unroll
                for (int mf = 0; mf < 4; ++mf) a[mf] = HB_READ(mf, kf);
#pragma unroll
                for (int nf = 0; nf < 8; ++nf) {
                    short8 b = WL_READ(1, nf, kf);
#pragma unroll
                    for (int mf = 0; mf < 4; ++mf)
                        acc[mf][nf] = __builtin_amdgcn_mfma_f32_16x16x32_bf16(a[mf], b, acc[mf][nf], 0, 0, 0);
                }
            }
            float Cw[4][4];
#pragma unroll
            for (int mf = 0; mf < 4; ++mf)
#pragma unroll
                for (int q = 0; q < 4; ++q)
                    Cw[mf][q] = 0.5f * (__cosf(dd[mf][q] * PI_OVER_CUTOFF) + 1.0f);
#pragma unroll
            for (int mf = 0; mf < 4; ++mf)
#pragma unroll
                for (int nf = 0; nf < 8; ++nf) {
                    f32x4 vv = acc[mf][nf];
#pragma unroll
                    for (int q = 0; q < 4; ++q) vv[q] = vv[q] * Cw[mf][q];
                    unsigned p01 = cvt_pk_bf16(vv[0], vv[1]);
                    unsigned p23 = cvt_pk_bf16(vv[2], vv[3]);
                    int col2 = (nf * 16 + l15) * 2;
                    int rb = mf * 16 + l4 * 4;
                    *(unsigned short*)(hb + (rb + 0) * 256 + (col2 ^ ((l4 * 4 + 0) << 4))) = (unsigned short)p01;
                    *(unsigned short*)(hb + (rb + 1) * 256 + (col2 ^ ((l4 * 4 + 1) << 4))) = (unsigned short)(p01 >> 16);
                    *(unsigned short*)(hb + (rb + 2) * 256 + (col2 ^ ((l4 * 4 + 2) << 4))) = (unsigned short)p23;
                    *(unsigned short*)(hb + (rb + 3) * 256 + (col2 ^ ((l4 * 4 + 3) << 4))) = (unsigned short)(p23 >> 16);
                }

            // ===== stage 4: out = (vp[j] .* W) @ (wo + I).T + bo =====
            INIT_ACC(bbo)
#pragma unroll
            for (int kf = 0; kf < 4; ++kf) {
                short8 a[4];
#pragma unroll
                for (int mf = 0; mf < 4; ++mf) a[mf] = mulbf8(HB_READ(mf, kf), vpr[mf][kf]);
#pragma unroll
                for (int nf = 0; nf < 8; ++nf) {
                    short8 b = WL_READ(2, nf, kf);
#pragma unroll
                    for (int mf = 0; mf < 4; ++mf)
                        acc[mf][nf] = __builtin_amdgcn_mfma_f32_16x16x32_bf16(a[mf], b, acc[mf][nf], 0, 0, 0);
                }
            }
            float* op = out + (size_t)e0 * 128;
#pragma unroll
            for (int mf = 0; mf < 4; ++mf)
#pragma unroll
                for (int nf = 0; nf < 8; ++nf)
#pragma unroll
                    for (int q = 0; q < 4; ++q)
                        op[(size_t)(mf * 16 + l4 * 4 + q) * 128 + nf * 16 + l15] = acc[mf][nf][q];
        }
    }
#undef EPILOGUE_TO_LDS
#undef INIT_ACC
#undef HB_READ
#undef WL_READ
}

extern "C" void kernel_launch(void* const* d_in, const int* in_sizes, int n_in,
                              void* d_out, int out_size, void* d_ws, size_t ws_size,
                              hipStream_t stream) {
    const float* v        = (const float*)d_in[0];
    const float* dist     = (const float*)d_in[1];
    const float* dist_emb = (const float*)d_in[2];
    const int*   edge_idx = (const int*)d_in[3];
    const float* lin_w    = (const float*)d_in[4];
    const float* w1 = (const float*)d_in[5];
    const float* b1 = (const float*)d_in[6];
    const float* w2 = (const float*)d_in[7];
    const float* b2 = (const float*)d_in[8];
    const float* w3 = (const float*)d_in[9];
    const float* b3 = (const float*)d_in[10];
    const float* wo = (const float*)d_in[11];
    const float* bo = (const float*)d_in[12];
    float* out = (float*)d_out;

    const int nnodes = in_sizes[0] / 128;   // 50000
    const int E = in_sizes[1];              // 1600000 (multiple of 256)
    const int ntiles = E / 256;

    unsigned short* vp   = (unsigned short*)d_ws;           // [nnodes][128] bf16
    unsigned short* w1p  = vp + (size_t)nnodes * 128;       // [128][64] row-major
    unsigned short* wsrc = w1p + 128 * 64;                  // 3x[128][128] swizzled

    prep_weights<<<64, 256, 0, stream>>>(w1, w2, w3, wo, w1p, wsrc);
    vp_gemm<<<(nnodes + 63) / 64, 256, 0, stream>>>(v, lin_w, vp, nnodes);
    fused_edge<<<256, 256, 0, stream>>>(dist, dist_emb, edge_idx,
                                        b1, b2, b3, bo, vp, w1p, wsrc, out, ntiles);
}

// Round 11
// 549.860 us; speedup vs baseline: 1.5659x; 1.5659x over previous
//
#include <hip/hip_runtime.h>
#include <math.h>

typedef __attribute__((ext_vector_type(8))) short short8;   // 8 bf16 (MFMA A/B frag)
typedef __attribute__((ext_vector_type(4))) float f32x4;    // MFMA acc frag
typedef __attribute__((ext_vector_type(2))) float f32x2;
typedef __attribute__((ext_vector_type(4))) unsigned u32x4;

#define PI_OVER_CUTOFF 0.31415926535897932f
#define SLOPE 0.015f

__device__ __forceinline__ unsigned short f2bf(float x) {
    unsigned u = __float_as_uint(x);
    return (unsigned short)((u + 0x7FFFu + ((u >> 16) & 1u)) >> 16);   // RNE
}
// packed f32x2 -> bf16x2, RNE, one instruction. D.lo = cvt(S0), D.hi = cvt(S1).
__device__ __forceinline__ unsigned cvt_pk_bf16(float lo, float hi) {
    unsigned r;
    asm("v_cvt_pk_bf16_f32 %0, %1, %2" : "=v"(r) : "v"(lo), "v"(hi));
    return r;
}
__device__ __forceinline__ short8 pack4(unsigned a, unsigned b, unsigned c, unsigned d) {
    u32x4 t = {a, b, c, d};
    return __builtin_bit_cast(short8, t);
}
// elementwise bf16 product of two bf16x8 frags, computed in f32, repacked bf16
__device__ __forceinline__ short8 mulbf8(short8 w, short8 v) {
    u32x4 uw = __builtin_bit_cast(u32x4, w);
    u32x4 uv = __builtin_bit_cast(u32x4, v);
    unsigned r0, r1, r2, r3;
#define MB(i, r)                                                         \
    {                                                                    \
        float wl = __uint_as_float(uw[i] << 16);                         \
        float wh = __uint_as_float(uw[i] & 0xFFFF0000u);                 \
        float vl = __uint_as_float(uv[i] << 16);                         \
        float vh = __uint_as_float(uv[i] & 0xFFFF0000u);                 \
        r = cvt_pk_bf16(wl * vl, wh * vh);                               \
    }
    MB(0, r0) MB(1, r1) MB(2, r2) MB(3, r3)
#undef MB
    return pack4(r0, r1, r2, r3);
}

// async global(per-lane) -> LDS(wave-uniform base, lane*16B) 16-byte copy
#define GLOAD_LDS16(g, l)                                                                      \
    __builtin_amdgcn_global_load_lds((const __attribute__((address_space(1))) unsigned*)(g),   \
                                     (__attribute__((address_space(3))) unsigned*)(l), 16, 0, 0)

// ---- kernel 0: weights -> bf16, B^T layout, PRE-SWIZZLED (R6-exact) ----------
// each [128][128]: (c,k) at c*128 + (k ^ ((c&15)<<3)); w1 zero-padded K 50->128.
__global__ void prep_weights(const float* __restrict__ w1, const float* __restrict__ w2,
                             const float* __restrict__ w3, const float* __restrict__ wo,
                             unsigned short* __restrict__ w1s, unsigned short* __restrict__ w2s,
                             unsigned short* __restrict__ w3s, unsigned short* __restrict__ wos) {
    int i = blockIdx.x * 256 + threadIdx.x;
    if (i < 128 * 128) {
        int c = i >> 7, k = i & 127;
        int d = c * 128 + (k ^ ((c & 15) << 3));
        w1s[d] = (k < 50) ? f2bf(w1[c * 50 + k]) : (unsigned short)0;
        w2s[d] = f2bf(w2[i]);
        w3s[d] = f2bf(w3[i]);
        wos[d] = f2bf(wo[i] + ((c == k) ? 1.0f : 0.0f));  // fold "+e" residual
    }
}

// ---------------- kernel 1: vp = v @ lin_w.T  -> bf16 [N][128] -----------------
__global__ __launch_bounds__(256) void vp_gemm(const float* __restrict__ v,
                                               const float* __restrict__ lin_w,
                                               unsigned short* __restrict__ vp, int nnodes) {
    const int tid = threadIdx.x;
    const int lane = tid & 63;
    const int wv = tid >> 6;          // wave 0..3 -> col strip of 32
    const int l15 = lane & 15;
    const int l4 = lane >> 4;
    const int r0 = blockIdx.x * 64;
    const int c0 = wv * 32;

    f32x4 acc[4][2] = {};
#pragma unroll
    for (int kf = 0; kf < 4; ++kf) {
        short8 a[4];
#pragma unroll
        for (int mf = 0; mf < 4; ++mf) {
            int row = r0 + mf * 16 + l15;
            f32x4 x0 = {}, x1 = {};
            if (row < nnodes) {
                const float* p = v + (size_t)row * 128 + kf * 32 + l4 * 8;
                x0 = *reinterpret_cast<const f32x4*>(p);
                x1 = *reinterpret_cast<const f32x4*>(p + 4);
            }
            a[mf] = pack4(cvt_pk_bf16(x0[0], x0[1]), cvt_pk_bf16(x0[2], x0[3]),
                          cvt_pk_bf16(x1[0], x1[1]), cvt_pk_bf16(x1[2], x1[3]));
        }
        short8 b[2];
#pragma unroll
        for (int nf = 0; nf < 2; ++nf) {
            const float* p = lin_w + (size_t)(c0 + nf * 16 + l15) * 128 + kf * 32 + l4 * 8;
            f32x4 x0 = *reinterpret_cast<const f32x4*>(p);
            f32x4 x1 = *reinterpret_cast<const f32x4*>(p + 4);
            b[nf] = pack4(cvt_pk_bf16(x0[0], x0[1]), cvt_pk_bf16(x0[2], x0[3]),
                          cvt_pk_bf16(x1[0], x1[1]), cvt_pk_bf16(x1[2], x1[3]));
        }
#pragma unroll
        for (int mf = 0; mf < 4; ++mf)
#pragma unroll
            for (int nf = 0; nf < 2; ++nf)
                acc[mf][nf] = __builtin_amdgcn_mfma_f32_16x16x32_bf16(a[mf], b[nf], acc[mf][nf], 0, 0, 0);
    }
#pragma unroll
    for (int mf = 0; mf < 4; ++mf)
#pragma unroll
        for (int nf = 0; nf < 2; ++nf)
#pragma unroll
            for (int q = 0; q < 4; ++q) {
                int row = r0 + mf * 16 + l4 * 4 + q;
                if (row < nnodes)
                    vp[(size_t)row * 128 + c0 + nf * 16 + l15] = f2bf(acc[mf][nf][q]);
            }
}

// ---- kernel 2: R6 structure + intra-wave 2-half pipeline ---------------------
// 4 waves x 64 edges, relaunched blocks (E/256). Each wave's 64 rows split into
// two independent 32-row halves with private 8KB h regions; stages issued
// S1a S1b | S2a S2b | S3a S3b | S4a S4b so each half's latency hides under the
// sibling's compute. acc halves to [2][8] -> no spill at full 512-reg budget.
// Barriers/staging identical to R6 (the 527us champion).
__global__ __launch_bounds__(256, 1) void fused_edge(
    const float* __restrict__ dist, const float* __restrict__ dist_emb,
    const int* __restrict__ edge_index,
    const float* __restrict__ b1, const float* __restrict__ b2,
    const float* __restrict__ b3, const float* __restrict__ bo,
    const unsigned short* __restrict__ vp,
    const unsigned short* __restrict__ w1s, const unsigned short* __restrict__ w2s,
    const unsigned short* __restrict__ w3s, const unsigned short* __restrict__ wos,
    float* __restrict__ out) {
    __shared__ __align__(16) unsigned char lds_h[4][16384];    // per-wave: 2 halves x 8KB
    __shared__ __align__(16) unsigned short wbuf[2][16384];    // weight dbuf, swizzled

    const int tid = threadIdx.x;
    const int lane = tid & 63;
    const int wv = tid >> 6;
    const int l15 = lane & 15;
    const int l4 = lane >> 4;
    const long e0 = (long)blockIdx.x * 256 + wv * 64;
    unsigned char* h0 = lds_h[wv];
    unsigned char* h1 = lds_h[wv] + 8192;

#define STAGE_W(src, buf)                                                  \
    _Pragma("unroll")                                                      \
    for (int it = 0; it < 8; ++it) {                                       \
        int chunk = it * 4 + wv;                                           \
        GLOAD_LDS16((src) + chunk * 512 + lane * 8, &wbuf[buf][chunk * 512]); \
    }

    // prologue: stage w1 -> buf0, w2 -> buf1
    STAGE_W(w1s, 0)
    STAGE_W(w2s, 1)

    // emb fragments for BOTH halves, loaded+converted at top (cover = staging)
    short8 ea[2][2], eb[2][2];   // [mf][kf], halves a/b
#define LOAD_EMB(E, OFS)                                                            \
    _Pragma("unroll")                                                               \
    for (int mf = 0; mf < 2; ++mf)                                                  \
        _Pragma("unroll")                                                           \
        for (int kf = 0; kf < 2; ++kf) {                                            \
            const float* src = dist_emb + (e0 + (OFS) + mf * 16 + l15) * 50 + kf * 32 + l4 * 8; \
            unsigned pk[4];                                                         \
            _Pragma("unroll")                                                       \
            for (int p = 0; p < 4; ++p) {                                           \
                int k2 = kf * 32 + l4 * 8 + 2 * p;                                  \
                f32x2 x = (k2 < 50) ? *reinterpret_cast<const f32x2*>(src + 2 * p)  \
                                    : (f32x2){0.f, 0.f};                            \
                pk[p] = cvt_pk_bf16(x[0], x[1]);                                    \
            }                                                                       \
            E[mf][kf] = pack4(pk[0], pk[1], pk[2], pk[3]);                          \
        }
    LOAD_EMB(ea, 0)
    LOAD_EMB(eb, 32)

    // hoist biases (col = nf*16 + l15; identity folded into wo)
    float bb1[8], bb2[8], bb3[8], bbo[8];
#pragma unroll
    for (int nf = 0; nf < 8; ++nf) {
        bb1[nf] = b1[nf * 16 + l15];
        bb2[nf] = b2[nf * 16 + l15];
        bb3[nf] = b3[nf * 16 + l15];
        bbo[nf] = bo[nf * 16 + l15];
    }

    f32x4 acc[2][8];

#define WB_READ(buf, nf, kf) \
    (*reinterpret_cast<const short8*>(&wbuf[buf][((nf) * 16 + l15) * 128 + (((kf) * 32 + l4 * 8) ^ (l15 << 3))]))
#define HB_READ(H, mf, kf) \
    (*reinterpret_cast<const short8*>((H) + ((mf) * 16 + l15) * 256 + (((kf) * 64 + l4 * 16) ^ (l15 << 4))))

#define INIT_ACC(bb)                                                                \
    _Pragma("unroll")                                                               \
    for (int nf = 0; nf < 8; ++nf) {                                                \
        float b = (bb)[nf];                                                         \
        acc[0][nf] = (f32x4){b, b, b, b};                                           \
        acc[1][nf] = acc[0][nf];                                                    \
    }

#define EPILOGUE_TO(H)                                                              \
    _Pragma("unroll")                                                               \
    for (int mf = 0; mf < 2; ++mf)                                                  \
        _Pragma("unroll")                                                           \
        for (int nf = 0; nf < 8; ++nf) {                                            \
            f32x4 vv = acc[mf][nf];                                                 \
            _Pragma("unroll")                                                       \
            for (int q = 0; q < 4; ++q) vv[q] = fmaxf(vv[q], SLOPE * vv[q]);        \
            unsigned p01 = cvt_pk_bf16(vv[0], vv[1]);                               \
            unsigned p23 = cvt_pk_bf16(vv[2], vv[3]);                               \
            int col2 = (nf * 16 + l15) * 2;                                         \
            int rb = mf * 16 + l4 * 4;                                              \
            *(unsigned short*)((H) + (rb + 0) * 256 + (col2 ^ ((l4 * 4 + 0) << 4))) = (unsigned short)p01;         \
            *(unsigned short*)((H) + (rb + 1) * 256 + (col2 ^ ((l4 * 4 + 1) << 4))) = (unsigned short)(p01 >> 16); \
            *(unsigned short*)((H) + (rb + 2) * 256 + (col2 ^ ((l4 * 4 + 2) << 4))) = (unsigned short)p23;         \
            *(unsigned short*)((H) + (rb + 3) * 256 + (col2 ^ ((l4 * 4 + 3) << 4))) = (unsigned short)(p23 >> 16); \
        }

// stage 1 for one half: h = leaky(emb @ w1.T + b1)
#define S1_BODY(E, H)                                                               \
    INIT_ACC(bb1)                                                                   \
    _Pragma("unroll")                                                               \
    for (int kf = 0; kf < 2; ++kf) {                                                \
        _Pragma("unroll")                                                           \
        for (int nf = 0; nf < 8; ++nf) {                                            \
            short8 b = WB_READ(0, nf, kf);                                          \
            acc[0][nf] = __builtin_amdgcn_mfma_f32_16x16x32_bf16(E[0][kf], b, acc[0][nf], 0, 0, 0); \
            acc[1][nf] = __builtin_amdgcn_mfma_f32_16x16x32_bf16(E[1][kf], b, acc[1][nf], 0, 0, 0); \
        }                                                                           \
    }                                                                               \
    EPILOGUE_TO(H)

// generic middle stage: h' = leaky(h @ w.T + b)
#define S2_BODY(H, BUF, BB)                                                         \
    INIT_ACC(BB)                                                                    \
    _Pragma("unroll")                                                               \
    for (int kf = 0; kf < 4; ++kf) {                                                \
        short8 a0 = HB_READ(H, 0, kf);                                              \
        short8 a1 = HB_READ(H, 1, kf);                                              \
        _Pragma("unroll")                                                           \
        for (int nf = 0; nf < 8; ++nf) {                                            \
            short8 b = WB_READ(BUF, nf, kf);                                        \
            acc[0][nf] = __builtin_amdgcn_mfma_f32_16x16x32_bf16(a0, b, acc[0][nf], 0, 0, 0); \
            acc[1][nf] = __builtin_amdgcn_mfma_f32_16x16x32_bf16(a1, b, acc[1][nf], 0, 0, 0); \
        }                                                                           \
    }

// stage 3 epilogue: scale by C and write back
#define S3_EPI(H, DD)                                                               \
    {                                                                               \
        float Cw[2][4];                                                             \
        _Pragma("unroll")                                                           \
        for (int mf = 0; mf < 2; ++mf)                                              \
            _Pragma("unroll")                                                       \
            for (int q = 0; q < 4; ++q)                                             \
                Cw[mf][q] = 0.5f * (__cosf(DD[mf][q] * PI_OVER_CUTOFF) + 1.0f);     \
        _Pragma("unroll")                                                           \
        for (int mf = 0; mf < 2; ++mf)                                              \
            _Pragma("unroll")                                                       \
            for (int nf = 0; nf < 8; ++nf) {                                        \
                f32x4 vv = acc[mf][nf];                                             \
                _Pragma("unroll")                                                   \
                for (int q = 0; q < 4; ++q) vv[q] = vv[q] * Cw[mf][q];              \
                unsigned p01 = cvt_pk_bf16(vv[0], vv[1]);                           \
                unsigned p23 = cvt_pk_bf16(vv[2], vv[3]);                           \
                int col2 = (nf * 16 + l15) * 2;                                     \
                int rb = mf * 16 + l4 * 4;                                          \
                *(unsigned short*)((H) + (rb + 0) * 256 + (col2 ^ ((l4 * 4 + 0) << 4))) = (unsigned short)p01;         \
                *(unsigned short*)((H) + (rb + 1) * 256 + (col2 ^ ((l4 * 4 + 1) << 4))) = (unsigned short)(p01 >> 16); \
                *(unsigned short*)((H) + (rb + 2) * 256 + (col2 ^ ((l4 * 4 + 2) << 4))) = (unsigned short)p23;         \
                *(unsigned short*)((H) + (rb + 3) * 256 + (col2 ^ ((l4 * 4 + 3) << 4))) = (unsigned short)(p23 >> 16); \
            }                                                                       \
    }

// stage 4 for one half: out = (vp[j] .* W) @ (wo + I).T + bo
#define S4_BODY(H, V, OFS)                                                          \
    INIT_ACC(bbo)                                                                   \
    _Pragma("unroll")                                                               \
    for (int kf = 0; kf < 4; ++kf) {                                                \
        short8 a0 = mulbf8(HB_READ(H, 0, kf), V[0][kf]);                            \
        short8 a1 = mulbf8(HB_READ(H, 1, kf), V[1][kf]);                            \
        _Pragma("unroll")                                                           \
        for (int nf = 0; nf < 8; ++nf) {                                            \
            short8 b = WB_READ(1, nf, kf);                                          \
            acc[0][nf] = __builtin_amdgcn_mfma_f32_16x16x32_bf16(a0, b, acc[0][nf], 0, 0, 0); \
            acc[1][nf] = __builtin_amdgcn_mfma_f32_16x16x32_bf16(a1, b, acc[1][nf], 0, 0, 0); \
        }                                                                           \
    }                                                                               \
    {                                                                               \
        float* op = out + (size_t)(e0 + (OFS)) * 128;                               \
        _Pragma("unroll")                                                           \
        for (int mf = 0; mf < 2; ++mf)                                              \
            _Pragma("unroll")                                                       \
            for (int nf = 0; nf < 8; ++nf)                                          \
                _Pragma("unroll")                                                   \
                for (int q = 0; q < 4; ++q)                                         \
                    op[(size_t)(mf * 16 + l4 * 4 + q) * 128 + nf * 16 + l15] = acc[mf][nf][q]; \
    }

    __syncthreads();   // bar0: w1 (buf0) + w2 (buf1) staged

    // ===== stage 1, both halves =====
    S1_BODY(ea, h0)
    S1_BODY(eb, h1)

    __syncthreads();   // bar1: all waves done with buf0 (w1)
    STAGE_W(w3s, 0)    // prefetch w3; hides under stage 2

    // ===== stage 2, both halves =====
    S2_BODY(h0, 1, bb2)
    EPILOGUE_TO(h0)
    S2_BODY(h1, 1, bb2)
    EPILOGUE_TO(h1)

    __syncthreads();   // bar2: done with buf1 (w2); w3 staging drained
    STAGE_W(wos, 1)    // prefetch wo; hides under stage 3

    // ===== stage 3 + gather, both halves (staggered vp prefetch) =====
    const int ja0 = edge_index[e0 + l15] * 128;
    const int ja1 = edge_index[e0 + 16 + l15] * 128;
    short8 va[2][4];
#pragma unroll
    for (int kf = 0; kf < 4; ++kf) {
        va[0][kf] = *reinterpret_cast<const short8*>(vp + ja0 + kf * 32 + l4 * 8);
        va[1][kf] = *reinterpret_cast<const short8*>(vp + ja1 + kf * 32 + l4 * 8);
    }
    float da[2][4];
#pragma unroll
    for (int mf = 0; mf < 2; ++mf)
#pragma unroll
        for (int q = 0; q < 4; ++q)
            da[mf][q] = dist[e0 + mf * 16 + l4 * 4 + q];

    S2_BODY(h0, 0, bb3)
    S3_EPI(h0, da)

    const int jb0 = edge_index[e0 + 32 + l15] * 128;
    const int jb1 = edge_index[e0 + 48 + l15] * 128;
    short8 vb[2][4];
#pragma unroll
    for (int kf = 0; kf < 4; ++kf) {
        vb[0][kf] = *reinterpret_cast<const short8*>(vp + jb0 + kf * 32 + l4 * 8);
        vb[1][kf] = *reinterpret_cast<const short8*>(vp + jb1 + kf * 32 + l4 * 8);
    }
    float db[2][4];
#pragma unroll
    for (int mf = 0; mf < 2; ++mf)
#pragma unroll
        for (int q = 0; q < 4; ++q)
            db[mf][q] = dist[e0 + 32 + mf * 16 + l4 * 4 + q];

    S2_BODY(h1, 0, bb3)
    S3_EPI(h1, db)

    __syncthreads();   // bar3: done with buf0 (w3); wo staging drained

    // ===== stage 4, both halves =====
    S4_BODY(h0, va, 0)
    S4_BODY(h1, vb, 32)

#undef S4_BODY
#undef S3_EPI
#undef S2_BODY
#undef S1_BODY
#undef EPILOGUE_TO
#undef INIT_ACC
#undef HB_READ
#undef WB_READ
#undef LOAD_EMB
#undef STAGE_W
}

extern "C" void kernel_launch(void* const* d_in, const int* in_sizes, int n_in,
                              void* d_out, int out_size, void* d_ws, size_t ws_size,
                              hipStream_t stream) {
    const float* v        = (const float*)d_in[0];
    const float* dist     = (const float*)d_in[1];
    const float* dist_emb = (const float*)d_in[2];
    const int*   edge_idx = (const int*)d_in[3];
    const float* lin_w    = (const float*)d_in[4];
    const float* w1 = (const float*)d_in[5];
    const float* b1 = (const float*)d_in[6];
    const float* w2 = (const float*)d_in[7];
    const float* b2 = (const float*)d_in[8];
    const float* w3 = (const float*)d_in[9];
    const float* b3 = (const float*)d_in[10];
    const float* wo = (const float*)d_in[11];
    const float* bo = (const float*)d_in[12];
    float* out = (float*)d_out;

    const int nnodes = in_sizes[0] / 128;   // 50000
    const int E = in_sizes[1];              // 1600000 (multiple of 256)

    unsigned short* vp  = (unsigned short*)d_ws;            // [nnodes][128] bf16
    unsigned short* w1s = vp + (size_t)nnodes * 128;        // [128][128] swizzled (padded)
    unsigned short* w2s = w1s + 128 * 128;
    unsigned short* w3s = w2s + 128 * 128;
    unsigned short* wos = w3s + 128 * 128;

    prep_weights<<<64, 256, 0, stream>>>(w1, w2, w3, wo, w1s, w2s, w3s, wos);
    vp_gemm<<<(nnodes + 63) / 64, 256, 0, stream>>>(v, lin_w, vp, nnodes);
    fused_edge<<<E / 256, 256, 0, stream>>>(dist, dist_emb, edge_idx,
                                            b1, b2, b3, bo, vp,
                                            w1s, w2s, w3s, wos, out);
}

// Round 12
// 541.585 us; speedup vs baseline: 1.5899x; 1.0153x over previous
//
#include <hip/hip_runtime.h>
#include <math.h>

typedef __attribute__((ext_vector_type(8))) short short8;   // 8 bf16 (MFMA A/B frag)
typedef __attribute__((ext_vector_type(4))) float f32x4;    // MFMA acc frag
typedef __attribute__((ext_vector_type(2))) float f32x2;
typedef __attribute__((ext_vector_type(4))) unsigned u32x4;

#define PI_OVER_CUTOFF 0.31415926535897932f
#define SLOPE 0.015f

__device__ __forceinline__ unsigned short f2bf(float x) {
    unsigned u = __float_as_uint(x);
    return (unsigned short)((u + 0x7FFFu + ((u >> 16) & 1u)) >> 16);   // RNE
}
// packed f32x2 -> bf16x2, RNE, one instruction. D.lo = cvt(S0), D.hi = cvt(S1).
__device__ __forceinline__ unsigned cvt_pk_bf16(float lo, float hi) {
    unsigned r;
    asm("v_cvt_pk_bf16_f32 %0, %1, %2" : "=v"(r) : "v"(lo), "v"(hi));
    return r;
}
__device__ __forceinline__ short8 pack4(unsigned a, unsigned b, unsigned c, unsigned d) {
    u32x4 t = {a, b, c, d};
    return __builtin_bit_cast(short8, t);
}
// elementwise bf16 product of two bf16x8 frags, computed in f32, repacked bf16
__device__ __forceinline__ short8 mulbf8(short8 w, short8 v) {
    u32x4 uw = __builtin_bit_cast(u32x4, w);
    u32x4 uv = __builtin_bit_cast(u32x4, v);
    unsigned r0, r1, r2, r3;
#define MB(i, r)                                                         \
    {                                                                    \
        float wl = __uint_as_float(uw[i] << 16);                         \
        float wh = __uint_as_float(uw[i] & 0xFFFF0000u);                 \
        float vl = __uint_as_float(uv[i] << 16);                         \
        float vh = __uint_as_float(uv[i] & 0xFFFF0000u);                 \
        r = cvt_pk_bf16(wl * vl, wh * vh);                               \
    }
    MB(0, r0) MB(1, r1) MB(2, r2) MB(3, r3)
#undef MB
    return pack4(r0, r1, r2, r3);
}

// async global(per-lane) -> LDS(wave-uniform base, lane*16B) 16-byte copy
#define GLOAD_LDS16(g, l)                                                                      \
    __builtin_amdgcn_global_load_lds((const __attribute__((address_space(1))) unsigned*)(g),   \
                                     (__attribute__((address_space(3))) unsigned*)(l), 16, 0, 0)

// ---- kernel 0: weights -> bf16 (R10-exact) ------------------------------------
// w1p: [128][64] row-major, NOT swizzled (B-frag reads from global, L2-hot).
// wsrc: w2|w3|wo each [128][128], PRE-SWIZZLED: (c,k) at c*128 + (k ^ ((c&15)<<3))
//       -> linear global_load_lds + swizzled ds_read is conflict-free (R6-verified).
__global__ void prep_weights(const float* __restrict__ w1, const float* __restrict__ w2,
                             const float* __restrict__ w3, const float* __restrict__ wo,
                             unsigned short* __restrict__ w1p, unsigned short* __restrict__ wsrc) {
    int i = blockIdx.x * 256 + threadIdx.x;
    unsigned short* w2s = wsrc;
    unsigned short* w3s = wsrc + 128 * 128;
    unsigned short* wos = w3s + 128 * 128;
    if (i < 128 * 64) {
        int c = i >> 6, k = i & 63;
        w1p[i] = (k < 50) ? f2bf(w1[c * 50 + k]) : (unsigned short)0;  // pad K 50->64
    }
    if (i < 128 * 128) {
        int c = i >> 7, k = i & 127;
        int d = c * 128 + (k ^ ((c & 15) << 3));
        w2s[d] = f2bf(w2[i]);
        w3s[d] = f2bf(w3[i]);
        wos[d] = f2bf(wo[i] + ((c == k) ? 1.0f : 0.0f));  // fold "+e" residual
    }
}

// ---------------- kernel 1: vp = v @ lin_w.T  -> bf16 [N][128] -----------------
__global__ __launch_bounds__(256) void vp_gemm(const float* __restrict__ v,
                                               const float* __restrict__ lin_w,
                                               unsigned short* __restrict__ vp, int nnodes) {
    const int tid = threadIdx.x;
    const int lane = tid & 63;
    const int wv = tid >> 6;          // wave 0..3 -> col strip of 32
    const int l15 = lane & 15;
    const int l4 = lane >> 4;
    const int r0 = blockIdx.x * 64;
    const int c0 = wv * 32;

    f32x4 acc[4][2] = {};
#pragma unroll
    for (int kf = 0; kf < 4; ++kf) {
        short8 a[4];
#pragma unroll
        for (int mf = 0; mf < 4; ++mf) {
            int row = r0 + mf * 16 + l15;
            f32x4 x0 = {}, x1 = {};
            if (row < nnodes) {
                const float* p = v + (size_t)row * 128 + kf * 32 + l4 * 8;
                x0 = *reinterpret_cast<const f32x4*>(p);
                x1 = *reinterpret_cast<const f32x4*>(p + 4);
            }
            a[mf] = pack4(cvt_pk_bf16(x0[0], x0[1]), cvt_pk_bf16(x0[2], x0[3]),
                          cvt_pk_bf16(x1[0], x1[1]), cvt_pk_bf16(x1[2], x1[3]));
        }
        short8 b[2];
#pragma unroll
        for (int nf = 0; nf < 2; ++nf) {
            const float* p = lin_w + (size_t)(c0 + nf * 16 + l15) * 128 + kf * 32 + l4 * 8;
            f32x4 x0 = *reinterpret_cast<const f32x4*>(p);
            f32x4 x1 = *reinterpret_cast<const f32x4*>(p + 4);
            b[nf] = pack4(cvt_pk_bf16(x0[0], x0[1]), cvt_pk_bf16(x0[2], x0[3]),
                          cvt_pk_bf16(x1[0], x1[1]), cvt_pk_bf16(x1[2], x1[3]));
        }
#pragma unroll
        for (int mf = 0; mf < 4; ++mf)
#pragma unroll
            for (int nf = 0; nf < 2; ++nf)
                acc[mf][nf] = __builtin_amdgcn_mfma_f32_16x16x32_bf16(a[mf], b[nf], acc[mf][nf], 0, 0, 0);
    }
#pragma unroll
    for (int mf = 0; mf < 4; ++mf)
#pragma unroll
        for (int nf = 0; nf < 2; ++nf)
#pragma unroll
            for (int q = 0; q < 4; ++q) {
                int row = r0 + mf * 16 + l4 * 4 + q;
                if (row < nnodes)
                    vp[(size_t)row * 128 + c0 + nf * 16 + l15] = f2bf(acc[mf][nf][q]);
            }
}

// ---- kernel 2: R6 bodies, ONE barrier, all weights staged up-front -----------
// Relaunched blocks (E/256), 4 waves x 64 edges. w2|w3|wo staged ONCE into 96KB
// LDS at block top (R10 layout); w1 B-frags from global (L2-hot); h private
// 16KB/wave. 160KB total. Single __syncthreads; stages run with zero further
// barriers/drains. Relaunch overlap hides each block's staging prologue.
__global__ __launch_bounds__(256, 1) void fused_edge(
    const float* __restrict__ dist, const float* __restrict__ dist_emb,
    const int* __restrict__ edge_index,
    const float* __restrict__ b1, const float* __restrict__ b2,
    const float* __restrict__ b3, const float* __restrict__ bo,
    const unsigned short* __restrict__ vp,
    const unsigned short* __restrict__ w1p, const unsigned short* __restrict__ wsrc,
    float* __restrict__ out) {
    __shared__ __align__(16) unsigned short wlds[3 * 16384];  // 96KB: w2|w3|wo swizzled
    __shared__ __align__(16) unsigned char lds_h[4][16384];   // per-wave [64][256B] swizzled

    const int tid = threadIdx.x;
    const int lane = tid & 63;
    const int wv = tid >> 6;
    const int l15 = lane & 15;
    const int l4 = lane >> 4;
    const long e0 = (long)blockIdx.x * 256 + wv * 64;
    unsigned char* hb = lds_h[wv];

    // ---- stage w2|w3|wo: 96 chunks of 1KB, 24 per wave (one-shot) ----
#pragma unroll
    for (int it = 0; it < 24; ++it) {
        int chunk = it * 4 + wv;
        GLOAD_LDS16(wsrc + chunk * 512 + lane * 8, &wlds[chunk * 512]);
    }

    // ---- pre-barrier: everything that doesn't touch LDS ----
    // emb fragments (consumed stage 1) — latency hides under the staging drain
    short8 ea[4][2];
#pragma unroll
    for (int mf = 0; mf < 4; ++mf)
#pragma unroll
        for (int kf = 0; kf < 2; ++kf) {
            const float* src = dist_emb + (e0 + mf * 16 + l15) * 50 + kf * 32 + l4 * 8;
            unsigned pk[4];
#pragma unroll
            for (int p = 0; p < 4; ++p) {
                int k2 = kf * 32 + l4 * 8 + 2 * p;
                f32x2 x = (k2 < 50) ? *reinterpret_cast<const f32x2*>(src + 2 * p)
                                    : (f32x2){0.f, 0.f};
                pk[p] = cvt_pk_bf16(x[0], x[1]);
            }
            ea[mf][kf] = pack4(pk[0], pk[1], pk[2], pk[3]);
        }
    // edge indices + dist (consumed stages 3/4)
    int jm[4];
#pragma unroll
    for (int mf = 0; mf < 4; ++mf)
        jm[mf] = edge_index[e0 + mf * 16 + l15] * 128;
    float dd[4][4];
#pragma unroll
    for (int mf = 0; mf < 4; ++mf)
#pragma unroll
        for (int q = 0; q < 4; ++q)
            dd[mf][q] = dist[e0 + mf * 16 + l4 * 4 + q];
    // biases (col = nf*16 + l15; identity folded into wo)
    float bb1[8], bb2[8], bb3[8], bbo[8];
#pragma unroll
    for (int nf = 0; nf < 8; ++nf) {
        bb1[nf] = b1[nf * 16 + l15];
        bb2[nf] = b2[nf * 16 + l15];
        bb3[nf] = b3[nf * 16 + l15];
        bbo[nf] = bo[nf * 16 + l15];
    }

#define WL_READ(widx, nf, kf) \
    (*reinterpret_cast<const short8*>(&wlds[(widx) * 16384 + ((nf) * 16 + l15) * 128 + (((kf) * 32 + l4 * 8) ^ (l15 << 3))]))
#define HB_READ(mf, kf) \
    (*reinterpret_cast<const short8*>(hb + ((mf) * 16 + l15) * 256 + (((kf) * 64 + l4 * 16) ^ (l15 << 4))))

#define INIT_ACC(bb)                                                                \
    _Pragma("unroll")                                                               \
    for (int nf = 0; nf < 8; ++nf) {                                                \
        float b = (bb)[nf];                                                         \
        _Pragma("unroll")                                                           \
        for (int mf = 0; mf < 4; ++mf) acc[mf][nf] = (f32x4){b, b, b, b};           \
    }

#define EPILOGUE_TO_LDS()                                                           \
    _Pragma("unroll")                                                               \
    for (int mf = 0; mf < 4; ++mf)                                                  \
        _Pragma("unroll")                                                           \
        for (int nf = 0; nf < 8; ++nf) {                                            \
            f32x4 vv = acc[mf][nf];                                                 \
            _Pragma("unroll")                                                       \
            for (int q = 0; q < 4; ++q) vv[q] = fmaxf(vv[q], SLOPE * vv[q]);        \
            unsigned p01 = cvt_pk_bf16(vv[0], vv[1]);                               \
            unsigned p23 = cvt_pk_bf16(vv[2], vv[3]);                               \
            int col2 = (nf * 16 + l15) * 2;                                         \
            int rb = mf * 16 + l4 * 4;                                              \
            *(unsigned short*)(hb + (rb + 0) * 256 + (col2 ^ ((l4 * 4 + 0) << 4))) = (unsigned short)p01;         \
            *(unsigned short*)(hb + (rb + 1) * 256 + (col2 ^ ((l4 * 4 + 1) << 4))) = (unsigned short)(p01 >> 16); \
            *(unsigned short*)(hb + (rb + 2) * 256 + (col2 ^ ((l4 * 4 + 2) << 4))) = (unsigned short)p23;         \
            *(unsigned short*)(hb + (rb + 3) * 256 + (col2 ^ ((l4 * 4 + 3) << 4))) = (unsigned short)(p23 >> 16); \
        }

    __syncthreads();   // the ONLY barrier: 96KB weights staged (vmcnt drained)

    f32x4 acc[4][8];

    // ===== stage 1: h1 = leaky(emb @ w1.T + b1)  [w1 B-frags from global] =====
    INIT_ACC(bb1)
#pragma unroll
    for (int kf = 0; kf < 2; ++kf) {
#pragma unroll
        for (int nf = 0; nf < 8; ++nf) {
            short8 b = *reinterpret_cast<const short8*>(w1p + (nf * 16 + l15) * 64 + kf * 32 + l4 * 8);
#pragma unroll
            for (int mf = 0; mf < 4; ++mf)
                acc[mf][nf] = __builtin_amdgcn_mfma_f32_16x16x32_bf16(ea[mf][kf], b, acc[mf][nf], 0, 0, 0);
        }
    }
    EPILOGUE_TO_LDS()

    // ===== stage 2: h2 = leaky(h1 @ w2.T + b2) =====
    INIT_ACC(bb2)
#pragma unroll
    for (int kf = 0; kf < 4; ++kf) {
        short8 a[4];
#pragma unroll
        for (int mf = 0; mf < 4; ++mf) a[mf] = HB_READ(mf, kf);
#pragma unroll
        for (int nf = 0; nf < 8; ++nf) {
            short8 b = WL_READ(0, nf, kf);
#pragma unroll
            for (int mf = 0; mf < 4; ++mf)
                acc[mf][nf] = __builtin_amdgcn_mfma_f32_16x16x32_bf16(a[mf], b, acc[mf][nf], 0, 0, 0);
        }
    }
    EPILOGUE_TO_LDS()

    // ===== stage 3: W = (h2 @ w3.T + b3) * C(dist) =====
    {
        // vp gather issued at stage-3 top (R6 placement, 1 stage of cover)
        short8 vpr[4][4];
#pragma unroll
        for (int mf = 0; mf < 4; ++mf)
#pragma unroll
            for (int kf = 0; kf < 4; ++kf)
                vpr[mf][kf] = *reinterpret_cast<const short8*>(vp + jm[mf] + kf * 32 + l4 * 8);

        INIT_ACC(bb3)
#pragma unroll
        for (int kf = 0; kf < 4; ++kf) {
            short8 a[4];
#pragma unroll
            for (int mf = 0; mf < 4; ++mf) a[mf] = HB_READ(mf, kf);
#pragma unroll
            for (int nf = 0; nf < 8; ++nf) {
                short8 b = WL_READ(1, nf, kf);
#pragma unroll
                for (int mf = 0; mf < 4; ++mf)
                    acc[mf][nf] = __builtin_amdgcn_mfma_f32_16x16x32_bf16(a[mf], b, acc[mf][nf], 0, 0, 0);
            }
        }
        float Cw[4][4];
#pragma unroll
        for (int mf = 0; mf < 4; ++mf)
#pragma unroll
            for (int q = 0; q < 4; ++q)
                Cw[mf][q] = 0.5f * (__cosf(dd[mf][q] * PI_OVER_CUTOFF) + 1.0f);
#pragma unroll
        for (int mf = 0; mf < 4; ++mf)
#pragma unroll
            for (int nf = 0; nf < 8; ++nf) {
                f32x4 vv = acc[mf][nf];
#pragma unroll
                for (int q = 0; q < 4; ++q) vv[q] = vv[q] * Cw[mf][q];
                unsigned p01 = cvt_pk_bf16(vv[0], vv[1]);
                unsigned p23 = cvt_pk_bf16(vv[2], vv[3]);
                int col2 = (nf * 16 + l15) * 2;
                int rb = mf * 16 + l4 * 4;
                *(unsigned short*)(hb + (rb + 0) * 256 + (col2 ^ ((l4 * 4 + 0) << 4))) = (unsigned short)p01;
                *(unsigned short*)(hb + (rb + 1) * 256 + (col2 ^ ((l4 * 4 + 1) << 4))) = (unsigned short)(p01 >> 16);
                *(unsigned short*)(hb + (rb + 2) * 256 + (col2 ^ ((l4 * 4 + 2) << 4))) = (unsigned short)p23;
                *(unsigned short*)(hb + (rb + 3) * 256 + (col2 ^ ((l4 * 4 + 3) << 4))) = (unsigned short)(p23 >> 16);
            }

        // ===== stage 4: out = (vp[j] .* W) @ (wo + I).T + bo =====
        INIT_ACC(bbo)
#pragma unroll
        for (int kf = 0; kf < 4; ++kf) {
            short8 a[4];
#pragma unroll
            for (int mf = 0; mf < 4; ++mf) a[mf] = mulbf8(HB_READ(mf, kf), vpr[mf][kf]);
#pragma unroll
            for (int nf = 0; nf < 8; ++nf) {
                short8 b = WL_READ(2, nf, kf);
#pragma unroll
                for (int mf = 0; mf < 4; ++mf)
                    acc[mf][nf] = __builtin_amdgcn_mfma_f32_16x16x32_bf16(a[mf], b, acc[mf][nf], 0, 0, 0);
            }
        }
        float* op = out + (size_t)e0 * 128;
#pragma unroll
        for (int mf = 0; mf < 4; ++mf)
#pragma unroll
            for (int nf = 0; nf < 8; ++nf)
#pragma unroll
                for (int q = 0; q < 4; ++q)
                    op[(size_t)(mf * 16 + l4 * 4 + q) * 128 + nf * 16 + l15] = acc[mf][nf][q];
    }
#undef EPILOGUE_TO_LDS
#undef INIT_ACC
#undef HB_READ
#undef WL_READ
}

extern "C" void kernel_launch(void* const* d_in, const int* in_sizes, int n_in,
                              void* d_out, int out_size, void* d_ws, size_t ws_size,
                              hipStream_t stream) {
    const float* v        = (const float*)d_in[0];
    const float* dist     = (const float*)d_in[1];
    const float* dist_emb = (const float*)d_in[2];
    const int*   edge_idx = (const int*)d_in[3];
    const float* lin_w    = (const float*)d_in[4];
    const float* w1 = (const float*)d_in[5];
    const float* b1 = (const float*)d_in[6];
    const float* w2 = (const float*)d_in[7];
    const float* b2 = (const float*)d_in[8];
    const float* w3 = (const float*)d_in[9];
    const float* b3 = (const float*)d_in[10];
    const float* wo = (const float*)d_in[11];
    const float* bo = (const float*)d_in[12];
    float* out = (float*)d_out;

    const int nnodes = in_sizes[0] / 128;   // 50000
    const int E = in_sizes[1];              // 1600000 (multiple of 256)

    unsigned short* vp   = (unsigned short*)d_ws;           // [nnodes][128] bf16
    unsigned short* w1p  = vp + (size_t)nnodes * 128;       // [128][64] row-major
    unsigned short* wsrc = w1p + 128 * 64;                  // 3x[128][128] swizzled

    prep_weights<<<64, 256, 0, stream>>>(w1, w2, w3, wo, w1p, wsrc);
    vp_gemm<<<(nnodes + 63) / 64, 256, 0, stream>>>(v, lin_w, vp, nnodes);
    fused_edge<<<E / 256, 256, 0, stream>>>(dist, dist_emb, edge_idx,
                                            b1, b2, b3, bo, vp, w1p, wsrc, out);
}

// Round 13
// 525.989 us; speedup vs baseline: 1.6370x; 1.0296x over previous
//
#include <hip/hip_runtime.h>
#include <math.h>

typedef __attribute__((ext_vector_type(8))) short short8;   // 8 bf16 (MFMA A/B frag)
typedef __attribute__((ext_vector_type(4))) float f32x4;    // MFMA acc frag
typedef __attribute__((ext_vector_type(2))) float f32x2;
typedef __attribute__((ext_vector_type(4))) unsigned u32x4;

#define PI_OVER_CUTOFF 0.31415926535897932f
#define SLOPE 0.015f

__device__ __forceinline__ unsigned short f2bf(float x) {
    unsigned u = __float_as_uint(x);
    return (unsigned short)((u + 0x7FFFu + ((u >> 16) & 1u)) >> 16);   // RNE
}
// packed f32x2 -> bf16x2, RNE, one instruction. D.lo = cvt(S0), D.hi = cvt(S1).
__device__ __forceinline__ unsigned cvt_pk_bf16(float lo, float hi) {
    unsigned r;
    asm("v_cvt_pk_bf16_f32 %0, %1, %2" : "=v"(r) : "v"(lo), "v"(hi));
    return r;
}
__device__ __forceinline__ short8 pack4(unsigned a, unsigned b, unsigned c, unsigned d) {
    u32x4 t = {a, b, c, d};
    return __builtin_bit_cast(short8, t);
}
// elementwise bf16 product of two bf16x8 frags, computed in f32, repacked bf16
__device__ __forceinline__ short8 mulbf8(short8 w, short8 v) {
    u32x4 uw = __builtin_bit_cast(u32x4, w);
    u32x4 uv = __builtin_bit_cast(u32x4, v);
    unsigned r0, r1, r2, r3;
#define MB(i, r)                                                         \
    {                                                                    \
        float wl = __uint_as_float(uw[i] << 16);                         \
        float wh = __uint_as_float(uw[i] & 0xFFFF0000u);                 \
        float vl = __uint_as_float(uv[i] << 16);                         \
        float vh = __uint_as_float(uv[i] & 0xFFFF0000u);                 \
        r = cvt_pk_bf16(wl * vl, wh * vh);                               \
    }
    MB(0, r0) MB(1, r1) MB(2, r2) MB(3, r3)
#undef MB
    return pack4(r0, r1, r2, r3);
}

// async global(per-lane) -> LDS(wave-uniform base, lane*16B) 16-byte copy
#define GLOAD_LDS16(g, l)                                                                      \
    __builtin_amdgcn_global_load_lds((const __attribute__((address_space(1))) unsigned*)(g),   \
                                     (__attribute__((address_space(3))) unsigned*)(l), 16, 0, 0)

// ---- kernel 0: weights -> bf16, B^T layout, PRE-SWIZZLED for LDS staging -----
// element (row c, col k) stored at u16 index c*128 + (k ^ ((c&15)<<3)).
// linear global_load_lds then yields the same swizzled layout in LDS; the
// ds_read applies the identical XOR -> conflict-free (verified, R6: 0 conflicts).
__global__ void prep_weights(const float* __restrict__ w1, const float* __restrict__ w2,
                             const float* __restrict__ w3, const float* __restrict__ wo,
                             unsigned short* __restrict__ w1s, unsigned short* __restrict__ w2s,
                             unsigned short* __restrict__ w3s, unsigned short* __restrict__ wos) {
    int i = blockIdx.x * 256 + threadIdx.x;
    if (i < 128 * 128) {
        int c = i >> 7, k = i & 127;
        int d = c * 128 + (k ^ ((c & 15) << 3));
        w1s[d] = (k < 50) ? f2bf(w1[c * 50 + k]) : (unsigned short)0;  // pad K 50->128
        w2s[d] = f2bf(w2[i]);
        w3s[d] = f2bf(w3[i]);
        wos[d] = f2bf(wo[i] + ((c == k) ? 1.0f : 0.0f));  // fold "+e" residual
    }
}

// ---------------- kernel 1: vp = v @ lin_w.T  -> bf16 [N][128] -----------------
__global__ __launch_bounds__(256) void vp_gemm(const float* __restrict__ v,
                                               const float* __restrict__ lin_w,
                                               unsigned short* __restrict__ vp, int nnodes) {
    const int tid = threadIdx.x;
    const int lane = tid & 63;
    const int wv = tid >> 6;          // wave 0..3 -> col strip of 32
    const int l15 = lane & 15;
    const int l4 = lane >> 4;
    const int r0 = blockIdx.x * 64;
    const int c0 = wv * 32;

    f32x4 acc[4][2] = {};
#pragma unroll
    for (int kf = 0; kf < 4; ++kf) {
        short8 a[4];
#pragma unroll
        for (int mf = 0; mf < 4; ++mf) {
            int row = r0 + mf * 16 + l15;
            f32x4 x0 = {}, x1 = {};
            if (row < nnodes) {
                const float* p = v + (size_t)row * 128 + kf * 32 + l4 * 8;
                x0 = *reinterpret_cast<const f32x4*>(p);
                x1 = *reinterpret_cast<const f32x4*>(p + 4);
            }
            a[mf] = pack4(cvt_pk_bf16(x0[0], x0[1]), cvt_pk_bf16(x0[2], x0[3]),
                          cvt_pk_bf16(x1[0], x1[1]), cvt_pk_bf16(x1[2], x1[3]));
        }
        short8 b[2];
#pragma unroll
        for (int nf = 0; nf < 2; ++nf) {
            const float* p = lin_w + (size_t)(c0 + nf * 16 + l15) * 128 + kf * 32 + l4 * 8;
            f32x4 x0 = *reinterpret_cast<const f32x4*>(p);
            f32x4 x1 = *reinterpret_cast<const f32x4*>(p + 4);
            b[nf] = pack4(cvt_pk_bf16(x0[0], x0[1]), cvt_pk_bf16(x0[2], x0[3]),
                          cvt_pk_bf16(x1[0], x1[1]), cvt_pk_bf16(x1[2], x1[3]));
        }
#pragma unroll
        for (int mf = 0; mf < 4; ++mf)
#pragma unroll
            for (int nf = 0; nf < 2; ++nf)
                acc[mf][nf] = __builtin_amdgcn_mfma_f32_16x16x32_bf16(a[mf], b[nf], acc[mf][nf], 0, 0, 0);
    }
#pragma unroll
    for (int mf = 0; mf < 4; ++mf)
#pragma unroll
        for (int nf = 0; nf < 2; ++nf)
#pragma unroll
            for (int q = 0; q < 4; ++q) {
                int row = r0 + mf * 16 + l4 * 4 + q;
                if (row < nnodes)
                    vp[(size_t)row * 128 + c0 + nf * 16 + l15] = f2bf(acc[mf][nf][q]);
            }
}

// ---------------- kernel 2: fused edge chain, LDS-staged weights --------------
// THE R6 CHAMPION (527us). 4 waves x 64 edges. Weights double-buffered in LDS
// (32KB slots), prefetched one stage ahead via global_load_lds; B-reads are
// conflict-free ds_read_b128. launch_bounds(256,1): 512-reg budget, no spill.
// Measured: MfmaUtil 13.3, VALUBusy 24, HBM 26%, traffic exactly ideal 1.19GB,
// 0 bank conflicts. R7-R12 tested persistence / TLP / intra-wave pipelining /
// barrier removal -- all land 542-861us. Remaining gap to the 190us HBM floor
// is exposed dependent-chain latency at 1 wave/SIMD (needs asm-level counted-
// vmcnt pipelining to break; out of scope for source-level HIP here).
__global__ __launch_bounds__(256, 1) void fused_edge(
    const float* __restrict__ dist, const float* __restrict__ dist_emb,
    const int* __restrict__ edge_index,
    const float* __restrict__ b1, const float* __restrict__ b2,
    const float* __restrict__ b3, const float* __restrict__ bo,
    const unsigned short* __restrict__ vp,
    const unsigned short* __restrict__ w1s, const unsigned short* __restrict__ w2s,
    const unsigned short* __restrict__ w3s, const unsigned short* __restrict__ wos,
    float* __restrict__ out) {
    __shared__ __align__(16) unsigned char lds_h[4][16384];    // per-wave h, swizzled
    __shared__ __align__(16) unsigned short wbuf[2][16384];    // weight dbuf, swizzled

    const int tid = threadIdx.x;
    const int lane = tid & 63;
    const int wv = tid >> 6;
    const int l15 = lane & 15;
    const int l4 = lane >> 4;
    const long e0 = (long)blockIdx.x * 256 + wv * 64;
    unsigned char* hb = lds_h[wv];

#define STAGE_W(src, buf)                                                  \
    _Pragma("unroll")                                                      \
    for (int it = 0; it < 8; ++it) {                                       \
        int chunk = it * 4 + wv;                                           \
        GLOAD_LDS16((src) + chunk * 512 + lane * 8, &wbuf[buf][chunk * 512]); \
    }

    // prologue: stage w1 -> buf0, w2 -> buf1; hoist indices + biases
    STAGE_W(w1s, 0)
    STAGE_W(w2s, 1)

    int jm[4];
#pragma unroll
    for (int mf = 0; mf < 4; ++mf)
        jm[mf] = edge_index[e0 + mf * 16 + l15] * 128;
    float bb1[8], bb2[8], bb3[8], bbo[8];
#pragma unroll
    for (int nf = 0; nf < 8; ++nf) {
        bb1[nf] = b1[nf * 16 + l15];
        bb2[nf] = b2[nf * 16 + l15];
        bb3[nf] = b3[nf * 16 + l15];
        bbo[nf] = bo[nf * 16 + l15];
    }

    f32x4 acc[4][8];

#define EPILOGUE_TO_LDS()                                                           \
    _Pragma("unroll")                                                               \
    for (int mf = 0; mf < 4; ++mf)                                                  \
        _Pragma("unroll")                                                           \
        for (int nf = 0; nf < 8; ++nf) {                                            \
            f32x4 vv = acc[mf][nf];                                                 \
            _Pragma("unroll")                                                       \
            for (int q = 0; q < 4; ++q) vv[q] = fmaxf(vv[q], SLOPE * vv[q]);        \
            unsigned p01 = cvt_pk_bf16(vv[0], vv[1]);                               \
            unsigned p23 = cvt_pk_bf16(vv[2], vv[3]);                               \
            int col2 = (nf * 16 + l15) * 2;                                         \
            int rb = mf * 16 + l4 * 4;                                              \
            *(unsigned short*)(hb + (rb + 0) * 256 + (col2 ^ ((l4 * 4 + 0) << 4))) = (unsigned short)p01;         \
            *(unsigned short*)(hb + (rb + 1) * 256 + (col2 ^ ((l4 * 4 + 1) << 4))) = (unsigned short)(p01 >> 16); \
            *(unsigned short*)(hb + (rb + 2) * 256 + (col2 ^ ((l4 * 4 + 2) << 4))) = (unsigned short)p23;         \
            *(unsigned short*)(hb + (rb + 3) * 256 + (col2 ^ ((l4 * 4 + 3) << 4))) = (unsigned short)(p23 >> 16); \
        }

#define HB_READ(mf, kf) \
    (*reinterpret_cast<const short8*>(hb + ((mf) * 16 + l15) * 256 + (((kf) * 64 + l4 * 16) ^ (l15 << 4))))
#define WB_READ(buf, nf, kf) \
    (*reinterpret_cast<const short8*>(&wbuf[buf][((nf) * 16 + l15) * 128 + (((kf) * 32 + l4 * 8) ^ (l15 << 3))]))

    __syncthreads();   // w1 (buf0) + w2 (buf1) staged

    // ================= stage 1: h1 = leaky(emb @ w1.T + b1) ==================
#pragma unroll
    for (int nf = 0; nf < 8; ++nf) {
        float b = bb1[nf];
#pragma unroll
        for (int mf = 0; mf < 4; ++mf) acc[mf][nf] = (f32x4){b, b, b, b};
    }
#pragma unroll
    for (int kf = 0; kf < 2; ++kf) {
        short8 a[4];
#pragma unroll
        for (int mf = 0; mf < 4; ++mf) {
            const float* src = dist_emb + (e0 + mf * 16 + l15) * 50 + kf * 32 + l4 * 8;
            unsigned pk[4];
#pragma unroll
            for (int p = 0; p < 4; ++p) {
                int k2 = kf * 32 + l4 * 8 + 2 * p;
                f32x2 x = (k2 < 50) ? *reinterpret_cast<const f32x2*>(src + 2 * p)
                                    : (f32x2){0.f, 0.f};
                pk[p] = cvt_pk_bf16(x[0], x[1]);
            }
            a[mf] = pack4(pk[0], pk[1], pk[2], pk[3]);
        }
#pragma unroll
        for (int nf = 0; nf < 8; ++nf) {
            short8 b = WB_READ(0, nf, kf);
#pragma unroll
            for (int mf = 0; mf < 4; ++mf)
                acc[mf][nf] = __builtin_amdgcn_mfma_f32_16x16x32_bf16(a[mf], b, acc[mf][nf], 0, 0, 0);
        }
    }
    EPILOGUE_TO_LDS()

    __syncthreads();   // all waves done reading buf0 (w1)
    STAGE_W(w3s, 0)    // prefetch w3 into buf0; hides under stage 2

    // ================= stage 2: h2 = leaky(h1 @ w2.T + b2) ====================
#pragma unroll
    for (int nf = 0; nf < 8; ++nf) {
        float b = bb2[nf];
#pragma unroll
        for (int mf = 0; mf < 4; ++mf) acc[mf][nf] = (f32x4){b, b, b, b};
    }
#pragma unroll
    for (int kf = 0; kf < 4; ++kf) {
        short8 a[4];
#pragma unroll
        for (int mf = 0; mf < 4; ++mf) a[mf] = HB_READ(mf, kf);
#pragma unroll
        for (int nf = 0; nf < 8; ++nf) {
            short8 b = WB_READ(1, nf, kf);
#pragma unroll
            for (int mf = 0; mf < 4; ++mf)
                acc[mf][nf] = __builtin_amdgcn_mfma_f32_16x16x32_bf16(a[mf], b, acc[mf][nf], 0, 0, 0);
        }
    }
    EPILOGUE_TO_LDS()

    __syncthreads();   // waves done with buf1 (w2); w3 staging drained
    STAGE_W(wos, 1)    // prefetch wo into buf1; hides under stage 3

    // ====== stage 3: W = (h2 @ w3.T + b3) * C  -> LDS (bf16) ==================
    {
        // vp gather prefetch: issued NOW, consumed in stage 4 (latency hidden
        // under stage-3 ds_reads + MFMAs). 64 VGPRs, affordable at 512 budget.
        short8 vpr[4][4];
#pragma unroll
        for (int mf = 0; mf < 4; ++mf)
#pragma unroll
            for (int kf = 0; kf < 4; ++kf)
                vpr[mf][kf] = *reinterpret_cast<const short8*>(vp + jm[mf] + kf * 32 + l4 * 8);

        float dd[4][4];
#pragma unroll
        for (int mf = 0; mf < 4; ++mf)
#pragma unroll
            for (int q = 0; q < 4; ++q)
                dd[mf][q] = dist[e0 + mf * 16 + l4 * 4 + q];

#pragma unroll
        for (int nf = 0; nf < 8; ++nf) {
            float b = bb3[nf];
#pragma unroll
            for (int mf = 0; mf < 4; ++mf) acc[mf][nf] = (f32x4){b, b, b, b};
        }
#pragma unroll
        for (int kf = 0; kf < 4; ++kf) {
            short8 a[4];
#pragma unroll
            for (int mf = 0; mf < 4; ++mf) a[mf] = HB_READ(mf, kf);
#pragma unroll
            for (int nf = 0; nf < 8; ++nf) {
                short8 b = WB_READ(0, nf, kf);
#pragma unroll
                for (int mf = 0; mf < 4; ++mf)
                    acc[mf][nf] = __builtin_amdgcn_mfma_f32_16x16x32_bf16(a[mf], b, acc[mf][nf], 0, 0, 0);
            }
        }
        float Cw[4][4];
#pragma unroll
        for (int mf = 0; mf < 4; ++mf)
#pragma unroll
            for (int q = 0; q < 4; ++q)
                Cw[mf][q] = 0.5f * (__cosf(dd[mf][q] * PI_OVER_CUTOFF) + 1.0f);
#pragma unroll
        for (int mf = 0; mf < 4; ++mf)
#pragma unroll
            for (int nf = 0; nf < 8; ++nf) {
                f32x4 vv = acc[mf][nf];
#pragma unroll
                for (int q = 0; q < 4; ++q) vv[q] = vv[q] * Cw[mf][q];
                unsigned p01 = cvt_pk_bf16(vv[0], vv[1]);
                unsigned p23 = cvt_pk_bf16(vv[2], vv[3]);
                int col2 = (nf * 16 + l15) * 2;
                int rb = mf * 16 + l4 * 4;
                *(unsigned short*)(hb + (rb + 0) * 256 + (col2 ^ ((l4 * 4 + 0) << 4))) = (unsigned short)p01;
                *(unsigned short*)(hb + (rb + 1) * 256 + (col2 ^ ((l4 * 4 + 1) << 4))) = (unsigned short)(p01 >> 16);
                *(unsigned short*)(hb + (rb + 2) * 256 + (col2 ^ ((l4 * 4 + 2) << 4))) = (unsigned short)p23;
                *(unsigned short*)(hb + (rb + 3) * 256 + (col2 ^ ((l4 * 4 + 3) << 4))) = (unsigned short)(p23 >> 16);
            }

        __syncthreads();   // waves done with buf0 (w3); wo staging drained

        // ====== stage 4: out = (vp[j] .* W) @ (wo + I).T + bo =================
#pragma unroll
        for (int nf = 0; nf < 8; ++nf) {
            float b = bbo[nf];
#pragma unroll
            for (int mf = 0; mf < 4; ++mf) acc[mf][nf] = (f32x4){b, b, b, b};
        }
#pragma unroll
        for (int kf = 0; kf < 4; ++kf) {
            short8 a[4];
#pragma unroll
            for (int mf = 0; mf < 4; ++mf) a[mf] = mulbf8(HB_READ(mf, kf), vpr[mf][kf]);
#pragma unroll
            for (int nf = 0; nf < 8; ++nf) {
                short8 b = WB_READ(1, nf, kf);
#pragma unroll
                for (int mf = 0; mf < 4; ++mf)
                    acc[mf][nf] = __builtin_amdgcn_mfma_f32_16x16x32_bf16(a[mf], b, acc[mf][nf], 0, 0, 0);
            }
        }
        float* op = out + (size_t)e0 * 128;
#pragma unroll
        for (int mf = 0; mf < 4; ++mf)
#pragma unroll
            for (int nf = 0; nf < 8; ++nf)
#pragma unroll
                for (int q = 0; q < 4; ++q)
                    op[(size_t)(mf * 16 + l4 * 4 + q) * 128 + nf * 16 + l15] = acc[mf][nf][q];
    }
#undef EPILOGUE_TO_LDS
#undef HB_READ
#undef WB_READ
#undef STAGE_W
}

extern "C" void kernel_launch(void* const* d_in, const int* in_sizes, int n_in,
                              void* d_out, int out_size, void* d_ws, size_t ws_size,
                              hipStream_t stream) {
    const float* v        = (const float*)d_in[0];
    const float* dist     = (const float*)d_in[1];
    const float* dist_emb = (const float*)d_in[2];
    const int*   edge_idx = (const int*)d_in[3];
    const float* lin_w    = (const float*)d_in[4];
    const float* w1 = (const float*)d_in[5];
    const float* b1 = (const float*)d_in[6];
    const float* w2 = (const float*)d_in[7];
    const float* b2 = (const float*)d_in[8];
    const float* w3 = (const float*)d_in[9];
    const float* b3 = (const float*)d_in[10];
    const float* wo = (const float*)d_in[11];
    const float* bo = (const float*)d_in[12];
    float* out = (float*)d_out;

    const int nnodes = in_sizes[0] / 128;   // 50000
    const int E = in_sizes[1];              // 1600000 (multiple of 256)

    unsigned short* vp  = (unsigned short*)d_ws;            // [nnodes][128] bf16
    unsigned short* w1s = vp + (size_t)nnodes * 128;        // [128][128] swizzled (padded)
    unsigned short* w2s = w1s + 128 * 128;
    unsigned short* w3s = w2s + 128 * 128;
    unsigned short* wos = w3s + 128 * 128;

    prep_weights<<<64, 256, 0, stream>>>(w1, w2, w3, wo, w1s, w2s, w3s, wos);
    vp_gemm<<<(nnodes + 63) / 64, 256, 0, stream>>>(v, lin_w, vp, nnodes);
    fused_edge<<<E / 256, 256, 0, stream>>>(dist, dist_emb, edge_idx,
                                            b1, b2, b3, bo, vp,
                                            w1s, w2s, w3s, wos, out);
}

// Round 14
// 452.113 us; speedup vs baseline: 1.9045x; 1.1634x over previous
//
#include <hip/hip_runtime.h>
#include <math.h>

typedef __attribute__((ext_vector_type(8))) short short8;   // 8 bf16 (MFMA A/B frag)
typedef __attribute__((ext_vector_type(4))) float f32x4;    // MFMA acc frag
typedef __attribute__((ext_vector_type(2))) float f32x2;
typedef __attribute__((ext_vector_type(4))) unsigned u32x4;

#define PI_OVER_CUTOFF 0.31415926535897932f
#define SLOPE 0.015f

__device__ __forceinline__ unsigned short f2bf(float x) {
    unsigned u = __float_as_uint(x);
    return (unsigned short)((u + 0x7FFFu + ((u >> 16) & 1u)) >> 16);   // RNE
}
// packed f32x2 -> bf16x2, RNE, one instruction. D.lo = cvt(S0), D.hi = cvt(S1).
__device__ __forceinline__ unsigned cvt_pk_bf16(float lo, float hi) {
    unsigned r;
    asm("v_cvt_pk_bf16_f32 %0, %1, %2" : "=v"(r) : "v"(lo), "v"(hi));
    return r;
}
__device__ __forceinline__ short8 pack4(unsigned a, unsigned b, unsigned c, unsigned d) {
    u32x4 t = {a, b, c, d};
    return __builtin_bit_cast(short8, t);
}
// elementwise bf16 product of two bf16x8 frags, computed in f32, repacked bf16
__device__ __forceinline__ short8 mulbf8(short8 w, short8 v) {
    u32x4 uw = __builtin_bit_cast(u32x4, w);
    u32x4 uv = __builtin_bit_cast(u32x4, v);
    unsigned r0, r1, r2, r3;
#define MB(i, r)                                                         \
    {                                                                    \
        float wl = __uint_as_float(uw[i] << 16);                         \
        float wh = __uint_as_float(uw[i] & 0xFFFF0000u);                 \
        float vl = __uint_as_float(uv[i] << 16);                         \
        float vh = __uint_as_float(uv[i] & 0xFFFF0000u);                 \
        r = cvt_pk_bf16(wl * vl, wh * vh);                               \
    }
    MB(0, r0) MB(1, r1) MB(2, r2) MB(3, r3)
#undef MB
    return pack4(r0, r1, r2, r3);
}

// async global(per-lane) -> LDS(wave-uniform base, lane*16B) 16-byte copy
#define GLOAD_LDS16(g, l)                                                                      \
    __builtin_amdgcn_global_load_lds((const __attribute__((address_space(1))) unsigned*)(g),   \
                                     (__attribute__((address_space(3))) unsigned*)(l), 16, 0, 0)

// ---- kernel 0: weights -> bf16 (R10/R12-exact) --------------------------------
// w1p: [128][64] row-major, NOT swizzled (B-frag reads from global, L1-hot).
// wsrc: w2|w3|wo each [128][128], PRE-SWIZZLED: (c,k) at c*128 + (k ^ ((c&15)<<3))
//       -> linear global_load_lds + swizzled ds_read is conflict-free (R6-verified).
__global__ void prep_weights(const float* __restrict__ w1, const float* __restrict__ w2,
                             const float* __restrict__ w3, const float* __restrict__ wo,
                             unsigned short* __restrict__ w1p, unsigned short* __restrict__ wsrc) {
    int i = blockIdx.x * 256 + threadIdx.x;
    unsigned short* w2s = wsrc;
    unsigned short* w3s = wsrc + 128 * 128;
    unsigned short* wos = w3s + 128 * 128;
    if (i < 128 * 64) {
        int c = i >> 6, k = i & 63;
        w1p[i] = (k < 50) ? f2bf(w1[c * 50 + k]) : (unsigned short)0;  // pad K 50->64
    }
    if (i < 128 * 128) {
        int c = i >> 7, k = i & 127;
        int d = c * 128 + (k ^ ((c & 15) << 3));
        w2s[d] = f2bf(w2[i]);
        w3s[d] = f2bf(w3[i]);
        wos[d] = f2bf(wo[i] + ((c == k) ? 1.0f : 0.0f));  // fold "+e" residual
    }
}

// ---------------- kernel 1: vp = v @ lin_w.T  -> bf16 [N][128] -----------------
__global__ __launch_bounds__(256) void vp_gemm(const float* __restrict__ v,
                                               const float* __restrict__ lin_w,
                                               unsigned short* __restrict__ vp, int nnodes) {
    const int tid = threadIdx.x;
    const int lane = tid & 63;
    const int wv = tid >> 6;          // wave 0..3 -> col strip of 32
    const int l15 = lane & 15;
    const int l4 = lane >> 4;
    const int r0 = blockIdx.x * 64;
    const int c0 = wv * 32;

    f32x4 acc[4][2] = {};
#pragma unroll
    for (int kf = 0; kf < 4; ++kf) {
        short8 a[4];
#pragma unroll
        for (int mf = 0; mf < 4; ++mf) {
            int row = r0 + mf * 16 + l15;
            f32x4 x0 = {}, x1 = {};
            if (row < nnodes) {
                const float* p = v + (size_t)row * 128 + kf * 32 + l4 * 8;
                x0 = *reinterpret_cast<const f32x4*>(p);
                x1 = *reinterpret_cast<const f32x4*>(p + 4);
            }
            a[mf] = pack4(cvt_pk_bf16(x0[0], x0[1]), cvt_pk_bf16(x0[2], x0[3]),
                          cvt_pk_bf16(x1[0], x1[1]), cvt_pk_bf16(x1[2], x1[3]));
        }
        short8 b[2];
#pragma unroll
        for (int nf = 0; nf < 2; ++nf) {
            const float* p = lin_w + (size_t)(c0 + nf * 16 + l15) * 128 + kf * 32 + l4 * 8;
            f32x4 x0 = *reinterpret_cast<const f32x4*>(p);
            f32x4 x1 = *reinterpret_cast<const f32x4*>(p + 4);
            b[nf] = pack4(cvt_pk_bf16(x0[0], x0[1]), cvt_pk_bf16(x0[2], x0[3]),
                          cvt_pk_bf16(x1[0], x1[1]), cvt_pk_bf16(x1[2], x1[3]));
        }
#pragma unroll
        for (int mf = 0; mf < 4; ++mf)
#pragma unroll
            for (int nf = 0; nf < 2; ++nf)
                acc[mf][nf] = __builtin_amdgcn_mfma_f32_16x16x32_bf16(a[mf], b[nf], acc[mf][nf], 0, 0, 0);
    }
#pragma unroll
    for (int mf = 0; mf < 4; ++mf)
#pragma unroll
        for (int nf = 0; nf < 2; ++nf)
#pragma unroll
            for (int q = 0; q < 4; ++q) {
                int row = r0 + mf * 16 + l4 * 4 + q;
                if (row < nnodes)
                    vp[(size_t)row * 128 + c0 + nf * 16 + l15] = f2bf(acc[mf][nf][q]);
            }
}

// ---- kernel 2: M=48/wave, 80KB LDS -> 2 INDEPENDENT BLOCKS per CU ------------
// The one untried point: 4 waves x 48 edges, h 4x12KB + single 32KB wbuf = 80KB
// exactly -> 2 blocks/CU co-resident (2 waves/SIMD from INDEPENDENT blocks that
// drift freely -- unlike R8/R9's barrier-locked same-block waves). Register
// demand ~205 (acc 96, biases loaded per stage, vp streamed) < 256 budget at
// launch_bounds(256,2) -> no spill. One block's barriers/staging/LDS-chain
// stalls hide under the sibling block's MFMA stream.
__global__ __launch_bounds__(256, 2) void fused_edge(
    const float* __restrict__ dist, const float* __restrict__ dist_emb,
    const int* __restrict__ edge_index,
    const float* __restrict__ b1, const float* __restrict__ b2,
    const float* __restrict__ b3, const float* __restrict__ bo,
    const unsigned short* __restrict__ vp,
    const unsigned short* __restrict__ w1p, const unsigned short* __restrict__ wsrc,
    float* __restrict__ out, int E) {
    __shared__ __align__(16) unsigned short wbuf[16384];       // 32KB single buffer, swizzled
    __shared__ __align__(16) unsigned char lds_h[4][12288];    // per-wave [48][256B], swizzled

    const int tid = threadIdx.x;
    const int lane = tid & 63;
    const int wv = tid >> 6;
    const int l15 = lane & 15;
    const int l4 = lane >> 4;
    const long e0 = (long)blockIdx.x * 192 + wv * 48;
    const long eE = E;
    unsigned char* hb = lds_h[wv];
    const unsigned short* w2s = wsrc;
    const unsigned short* w3s = wsrc + 128 * 128;
    const unsigned short* wos = w3s + 128 * 128;

#define STAGE_W(src)                                                       \
    _Pragma("unroll")                                                      \
    for (int it = 0; it < 8; ++it) {                                       \
        int chunk = it * 4 + wv;                                           \
        GLOAD_LDS16((src) + chunk * 512 + lane * 8, &wbuf[chunk * 512]);   \
    }

    // issue w2 staging NOW; S1 (which doesn't touch wbuf) runs under it
    STAGE_W(w2s)

    // hoisted edge indices (clamped for the partial last block)
    int jm[3];
#pragma unroll
    for (int mf = 0; mf < 3; ++mf) {
        long er = e0 + mf * 16 + l15;
        if (er >= eE) er = eE - 1;
        jm[mf] = edge_index[er] * 128;
    }

    f32x4 acc[3][8];

#define INIT_ACC(bp)                                                                \
    _Pragma("unroll")                                                               \
    for (int nf = 0; nf < 8; ++nf) {                                                \
        float b = (bp)[nf * 16 + l15];                                              \
        _Pragma("unroll")                                                           \
        for (int mf = 0; mf < 3; ++mf) acc[mf][nf] = (f32x4){b, b, b, b};           \
    }

#define EPILOGUE_TO_LDS()                                                           \
    _Pragma("unroll")                                                               \
    for (int mf = 0; mf < 3; ++mf)                                                  \
        _Pragma("unroll")                                                           \
        for (int nf = 0; nf < 8; ++nf) {                                            \
            f32x4 vv = acc[mf][nf];                                                 \
            _Pragma("unroll")                                                       \
            for (int q = 0; q < 4; ++q) vv[q] = fmaxf(vv[q], SLOPE * vv[q]);        \
            unsigned p01 = cvt_pk_bf16(vv[0], vv[1]);                               \
            unsigned p23 = cvt_pk_bf16(vv[2], vv[3]);                               \
            int col2 = (nf * 16 + l15) * 2;                                         \
            int rb = mf * 16 + l4 * 4;                                              \
            *(unsigned short*)(hb + (rb + 0) * 256 + (col2 ^ ((l4 * 4 + 0) << 4))) = (unsigned short)p01;         \
            *(unsigned short*)(hb + (rb + 1) * 256 + (col2 ^ ((l4 * 4 + 1) << 4))) = (unsigned short)(p01 >> 16); \
            *(unsigned short*)(hb + (rb + 2) * 256 + (col2 ^ ((l4 * 4 + 2) << 4))) = (unsigned short)p23;         \
            *(unsigned short*)(hb + (rb + 3) * 256 + (col2 ^ ((l4 * 4 + 3) << 4))) = (unsigned short)(p23 >> 16); \
        }

#define HB_READ(mf, kf) \
    (*reinterpret_cast<const short8*>(hb + ((mf) * 16 + l15) * 256 + (((kf) * 64 + l4 * 16) ^ (l15 << 4))))
#define WB_READ(nf, kf) \
    (*reinterpret_cast<const short8*>(&wbuf[((nf) * 16 + l15) * 128 + (((kf) * 32 + l4 * 8) ^ (l15 << 3))]))

    // ===== stage 1: h1 = leaky(emb @ w1.T + b1)  [w1 B-frags from global] =====
    INIT_ACC(b1)
#pragma unroll
    for (int kf = 0; kf < 2; ++kf) {
        short8 a[3];
#pragma unroll
        for (int mf = 0; mf < 3; ++mf) {
            long er = e0 + mf * 16 + l15;
            if (er >= eE) er = eE - 1;
            const float* src = dist_emb + er * 50 + kf * 32 + l4 * 8;
            unsigned pk[4];
#pragma unroll
            for (int p = 0; p < 4; ++p) {
                int k2 = kf * 32 + l4 * 8 + 2 * p;
                f32x2 x = (k2 < 50) ? *reinterpret_cast<const f32x2*>(src + 2 * p)
                                    : (f32x2){0.f, 0.f};
                pk[p] = cvt_pk_bf16(x[0], x[1]);
            }
            a[mf] = pack4(pk[0], pk[1], pk[2], pk[3]);
        }
#pragma unroll
        for (int nf = 0; nf < 8; ++nf) {
            short8 b = *reinterpret_cast<const short8*>(w1p + (nf * 16 + l15) * 64 + kf * 32 + l4 * 8);
#pragma unroll
            for (int mf = 0; mf < 3; ++mf)
                acc[mf][nf] = __builtin_amdgcn_mfma_f32_16x16x32_bf16(a[mf], b, acc[mf][nf], 0, 0, 0);
        }
    }
    EPILOGUE_TO_LDS()

    __syncthreads();   // bar1: w2 staged (vmcnt drained)

    // ===== stage 2: h2 = leaky(h1 @ w2.T + b2) =====
    INIT_ACC(b2)
#pragma unroll
    for (int kf = 0; kf < 4; ++kf) {
        short8 a[3];
#pragma unroll
        for (int mf = 0; mf < 3; ++mf) a[mf] = HB_READ(mf, kf);
#pragma unroll
        for (int nf = 0; nf < 8; ++nf) {
            short8 b = WB_READ(nf, kf);
#pragma unroll
            for (int mf = 0; mf < 3; ++mf)
                acc[mf][nf] = __builtin_amdgcn_mfma_f32_16x16x32_bf16(a[mf], b, acc[mf][nf], 0, 0, 0);
        }
    }
    EPILOGUE_TO_LDS()

    __syncthreads();   // bar2: all waves done reading w2
    STAGE_W(w3s)
    __syncthreads();   // bar3: w3 staged

    // ===== stage 3: W = (h2 @ w3.T + b3) * C(dist) =====
    {
        // dist + first vp slice issued at top (consumed at epilogue / stage 4)
        float dd[3][4];
#pragma unroll
        for (int mf = 0; mf < 3; ++mf)
#pragma unroll
            for (int q = 0; q < 4; ++q) {
                long dr = e0 + mf * 16 + l4 * 4 + q;
                if (dr >= eE) dr = eE - 1;
                dd[mf][q] = dist[dr];
            }
        short8 vcur[3];
#pragma unroll
        for (int mf = 0; mf < 3; ++mf)
            vcur[mf] = *reinterpret_cast<const short8*>(vp + jm[mf] + l4 * 8);

        INIT_ACC(b3)
#pragma unroll
        for (int kf = 0; kf < 4; ++kf) {
            short8 a[3];
#pragma unroll
            for (int mf = 0; mf < 3; ++mf) a[mf] = HB_READ(mf, kf);
#pragma unroll
            for (int nf = 0; nf < 8; ++nf) {
                short8 b = WB_READ(nf, kf);
#pragma unroll
                for (int mf = 0; mf < 3; ++mf)
                    acc[mf][nf] = __builtin_amdgcn_mfma_f32_16x16x32_bf16(a[mf], b, acc[mf][nf], 0, 0, 0);
            }
        }
        float Cw[3][4];
#pragma unroll
        for (int mf = 0; mf < 3; ++mf)
#pragma unroll
            for (int q = 0; q < 4; ++q)
                Cw[mf][q] = 0.5f * (__cosf(dd[mf][q] * PI_OVER_CUTOFF) + 1.0f);
#pragma unroll
        for (int mf = 0; mf < 3; ++mf)
#pragma unroll
            for (int nf = 0; nf < 8; ++nf) {
                f32x4 vv = acc[mf][nf];
#pragma unroll
                for (int q = 0; q < 4; ++q) vv[q] = vv[q] * Cw[mf][q];
                unsigned p01 = cvt_pk_bf16(vv[0], vv[1]);
                unsigned p23 = cvt_pk_bf16(vv[2], vv[3]);
                int col2 = (nf * 16 + l15) * 2;
                int rb = mf * 16 + l4 * 4;
                *(unsigned short*)(hb + (rb + 0) * 256 + (col2 ^ ((l4 * 4 + 0) << 4))) = (unsigned short)p01;
                *(unsigned short*)(hb + (rb + 1) * 256 + (col2 ^ ((l4 * 4 + 1) << 4))) = (unsigned short)(p01 >> 16);
                *(unsigned short*)(hb + (rb + 2) * 256 + (col2 ^ ((l4 * 4 + 2) << 4))) = (unsigned short)p23;
                *(unsigned short*)(hb + (rb + 3) * 256 + (col2 ^ ((l4 * 4 + 3) << 4))) = (unsigned short)(p23 >> 16);
            }

        __syncthreads();   // bar4: all waves done reading w3
        STAGE_W(wos)
        __syncthreads();   // bar5: wo staged

        // ===== stage 4: out = (vp[j] .* W) @ (wo + I).T + bo  [vp streamed] =====
        INIT_ACC(bo)
#pragma unroll
        for (int kf = 0; kf < 4; ++kf) {
            short8 vnxt[3];
            if (kf < 3) {
#pragma unroll
                for (int mf = 0; mf < 3; ++mf)
                    vnxt[mf] = *reinterpret_cast<const short8*>(vp + jm[mf] + (kf + 1) * 32 + l4 * 8);
            }
            short8 a[3];
#pragma unroll
            for (int mf = 0; mf < 3; ++mf) a[mf] = mulbf8(HB_READ(mf, kf), vcur[mf]);
#pragma unroll
            for (int nf = 0; nf < 8; ++nf) {
                short8 b = WB_READ(nf, kf);
#pragma unroll
                for (int mf = 0; mf < 3; ++mf)
                    acc[mf][nf] = __builtin_amdgcn_mfma_f32_16x16x32_bf16(a[mf], b, acc[mf][nf], 0, 0, 0);
            }
#pragma unroll
            for (int mf = 0; mf < 3; ++mf) vcur[mf] = vnxt[mf];
        }
#pragma unroll
        for (int mf = 0; mf < 3; ++mf)
#pragma unroll
            for (int q = 0; q < 4; ++q) {
                long row = e0 + mf * 16 + l4 * 4 + q;
                if (row < eE) {
                    float* op = out + row * 128 + l15;
#pragma unroll
                    for (int nf = 0; nf < 8; ++nf)
                        op[nf * 16] = acc[mf][nf][q];
                }
            }
    }
#undef EPILOGUE_TO_LDS
#undef INIT_ACC
#undef HB_READ
#undef WB_READ
#undef STAGE_W
}

extern "C" void kernel_launch(void* const* d_in, const int* in_sizes, int n_in,
                              void* d_out, int out_size, void* d_ws, size_t ws_size,
                              hipStream_t stream) {
    const float* v        = (const float*)d_in[0];
    const float* dist     = (const float*)d_in[1];
    const float* dist_emb = (const float*)d_in[2];
    const int*   edge_idx = (const int*)d_in[3];
    const float* lin_w    = (const float*)d_in[4];
    const float* w1 = (const float*)d_in[5];
    const float* b1 = (const float*)d_in[6];
    const float* w2 = (const float*)d_in[7];
    const float* b2 = (const float*)d_in[8];
    const float* w3 = (const float*)d_in[9];
    const float* b3 = (const float*)d_in[10];
    const float* wo = (const float*)d_in[11];
    const float* bo = (const float*)d_in[12];
    float* out = (float*)d_out;

    const int nnodes = in_sizes[0] / 128;   // 50000
    const int E = in_sizes[1];              // 1600000
    const int ntiles = (E + 191) / 192;     // 192 edges per block (M=48 x 4 waves)

    unsigned short* vp   = (unsigned short*)d_ws;           // [nnodes][128] bf16
    unsigned short* w1p  = vp + (size_t)nnodes * 128;       // [128][64] row-major
    unsigned short* wsrc = w1p + 128 * 64;                  // 3x[128][128] swizzled

    prep_weights<<<64, 256, 0, stream>>>(w1, w2, w3, wo, w1p, wsrc);
    vp_gemm<<<(nnodes + 63) / 64, 256, 0, stream>>>(v, lin_w, vp, nnodes);
    fused_edge<<<ntiles, 256, 0, stream>>>(dist, dist_emb, edge_idx,
                                           b1, b2, b3, bo, vp, w1p, wsrc, out, E);
}